// Round 2
// baseline (836.486 us; speedup 1.0000x reference)
//
#include <hip/hip_runtime.h>
#include <math.h>

// Dims fixed by setup_inputs(): B=16, S=2048, D=1024, H=16, hd=64, P=8,
// cls=1, pma=8, recent=64, T=73.

#define Bn 16
#define Sn 2048
#define Dn 1024
#define Hn 16
#define Pn 8
#define Tn 73
#define RECn 64

// ---------------------------------------------------------------- mask dtype detect
// valid_mask may be pushed as uint8 (numpy bool) or int32 ("integer -> int*").
// uint8 prefix masks have nonzero bytes at offsets i%4 != 0; int32 0/1 values
// never do. Scan first B*S bytes, set flag=1 for uint8 layout.
__global__ void detect_mask_kernel(const unsigned char* __restrict__ raw,
                                   int* __restrict__ flag) {
    __shared__ int any;
    if (threadIdx.x == 0) any = 0;
    __syncthreads();
    int local = 0;
    for (int i = threadIdx.x; i < Bn * Sn; i += blockDim.x)
        if ((i & 3) && raw[i]) local = 1;
    if (local) any = 1; // benign race
    __syncthreads();
    if (threadIdx.x == 0) *flag = any;
}

__global__ void canon_mask_kernel(const void* __restrict__ raw,
                                  const int* __restrict__ flag,
                                  unsigned char* __restrict__ canon) {
    int i = blockIdx.x * blockDim.x + threadIdx.x;
    if (i >= Bn * Sn) return;
    unsigned char v;
    if (*flag)
        v = ((const unsigned char*)raw)[i] ? 1 : 0;
    else
        v = ((const int*)raw)[i] ? 1 : 0;
    canon[i] = v;
}

// ---------------------------------------------------------------- prep
__global__ void prep_kernel(const unsigned char* __restrict__ valid,
                            int* __restrict__ totals, int* __restrict__ rsrc,
                            float* __restrict__ maskf) {
    int b = blockIdx.x, t = threadIdx.x;
    const int SP = Sn - 1; // 2047
    __shared__ int lc[256];
    if (t < RECn) rsrc[b * RECn + t] = -1;

    int base = t * 8;
    unsigned char m[8];
    int cnt = 0;
#pragma unroll
    for (int i = 0; i < 8; i++) {
        int idx = base + i;
        m[i] = (idx < SP) ? valid[(size_t)b * Sn + 1 + idx] : (unsigned char)0;
        cnt += m[i] ? 1 : 0;
    }
    lc[t] = cnt;
    __syncthreads();
    for (int off = 1; off < 256; off <<= 1) {
        int add = (t >= off) ? lc[t - off] : 0;
        __syncthreads();
        lc[t] += add;
        __syncthreads();
    }
    int total = lc[255];
    int run = lc[t] - cnt; // exclusive prefix
#pragma unroll
    for (int i = 0; i < 8; i++) {
        if (m[i]) {
            run++;
            int rank = total - run;
            if (rank < RECn) rsrc[b * RECn + (RECn - 1 - rank)] = base + i + 1;
        }
    }
    if (t == 0) totals[b] = total;
    if (t < Tn) {
        float mv;
        if (t == 0) mv = valid[(size_t)b * Sn] ? 1.0f : 0.0f;
        else if (t < 1 + Pn) mv = 1.0f;
        else mv = ((t - 9) >= RECn - total) ? 1.0f : 0.0f;
        maskf[b * Tn + t] = mv;
    }
}

// ---------------------------------------------------------------- q = queries @ Wq^T + bq
__global__ void q_kernel(const float* __restrict__ queries,
                         const float* __restrict__ in_w,
                         const float* __restrict__ in_b,
                         float* __restrict__ q) {
    int wid = (blockIdx.x * blockDim.x + threadIdx.x) >> 6;
    int lane = threadIdx.x & 63;
    if (wid >= Pn * Dn) return;
    int p = wid >> 10, j = wid & 1023;
    float acc = 0.0f;
    for (int c = lane; c < Dn; c += 64)
        acc += queries[p * Dn + c] * in_w[(size_t)j * Dn + c];
#pragma unroll
    for (int off = 32; off > 0; off >>= 1) acc += __shfl_down(acc, off);
    if (lane == 0) q[wid] = acc + in_b[j];
}

// ---------------------------------------------------------------- A[hp,c] = (q_h[p] . Wk_h[:,c]) / 8 ; c0[hp] = (q_h[p] . bk_h)/8
__global__ void A_kernel(const float* __restrict__ q,
                         const float* __restrict__ in_w,
                         const float* __restrict__ in_b,
                         float* __restrict__ Amat, float* __restrict__ c0) {
    int hp = blockIdx.x;
    int h = hp >> 3, p = hp & 7;
    __shared__ float qs[64];
    if (threadIdx.x < 64) qs[threadIdx.x] = q[p * Dn + h * 64 + threadIdx.x];
    __syncthreads();
    for (int c = threadIdx.x; c < Dn; c += blockDim.x) {
        float acc = 0.0f;
#pragma unroll
        for (int d = 0; d < 64; d++)
            acc += qs[d] * in_w[(size_t)(Dn + h * 64 + d) * Dn + c];
        Amat[(size_t)hp * Dn + c] = acc * 0.125f;
    }
    if (threadIdx.x == 0) {
        float acc = 0.0f;
        for (int d = 0; d < 64; d++) acc += qs[d] * in_b[Dn + h * 64 + d];
        c0[hp] = acc * 0.125f;
    }
}

// ---------------------------------------------------------------- scores[b,hp,s] = hidden[b,s,:]@A[hp,:] + c0, masked
__global__ void scores_kernel(const float* __restrict__ hidden,
                              const float* __restrict__ Amat,
                              const float* __restrict__ c0,
                              const unsigned char* __restrict__ valid,
                              float* __restrict__ scores) {
    __shared__ float Ash[64][33]; // hidden tile [s][k]
    __shared__ float Bsh[64][33]; // A tile [hp][k]
    int m0 = blockIdx.x * 64;   // global row (b*2048+s)
    int n0 = blockIdx.y * 64;   // hp
    int tid = threadIdx.x, tx = tid & 15, ty = tid >> 4;
    float acc[4][4] = {};
    for (int k0 = 0; k0 < Dn; k0 += 32) {
        int r = tid >> 2, cc = (tid & 3) * 8;
        {
            const float* src = &hidden[(size_t)(m0 + r) * Dn + k0 + cc];
#pragma unroll
            for (int i = 0; i < 8; i++) Ash[r][cc + i] = src[i];
        }
        {
            const float* src = &Amat[(size_t)(n0 + r) * Dn + k0 + cc];
#pragma unroll
            for (int i = 0; i < 8; i++) Bsh[r][cc + i] = src[i];
        }
        __syncthreads();
#pragma unroll
        for (int kk = 0; kk < 32; kk++) {
            float a[4], bb[4];
#pragma unroll
            for (int i = 0; i < 4; i++) a[i] = Ash[ty * 4 + i][kk];
#pragma unroll
            for (int j = 0; j < 4; j++) bb[j] = Bsh[tx * 4 + j][kk];
#pragma unroll
            for (int i = 0; i < 4; i++)
#pragma unroll
                for (int j = 0; j < 4; j++)
                    acc[i][j] = fmaf(a[i], bb[j], acc[i][j]);
        }
        __syncthreads();
    }
#pragma unroll
    for (int i = 0; i < 4; i++) {
        int row = m0 + ty * 4 + i;
        int b = row >> 11, s = row & 2047;
        bool ok = valid[(size_t)b * Sn + s] != 0;
#pragma unroll
        for (int j = 0; j < 4; j++) {
            int hp = n0 + tx * 4 + j;
            float v = ok ? (acc[i][j] + c0[hp]) : -1.0e9f;
            scores[((size_t)b * 128 + hp) * Sn + s] = v;
        }
    }
}

// ---------------------------------------------------------------- softmax over s (rows of 2048)
__global__ void softmax_kernel(float* __restrict__ scores) {
    float* row = scores + (size_t)blockIdx.x * Sn;
    int t = threadIdx.x;
    __shared__ float red[256];
    float v[8];
    float mx = -1.0e30f;
#pragma unroll
    for (int i = 0; i < 8; i++) {
        v[i] = row[t + i * 256];
        mx = fmaxf(mx, v[i]);
    }
    red[t] = mx;
    __syncthreads();
    for (int off = 128; off > 0; off >>= 1) {
        if (t < off) red[t] = fmaxf(red[t], red[t + off]);
        __syncthreads();
    }
    mx = red[0];
    __syncthreads();
    float sum = 0.0f;
#pragma unroll
    for (int i = 0; i < 8; i++) {
        v[i] = expf(v[i] - mx);
        sum += v[i];
    }
    red[t] = sum;
    __syncthreads();
    for (int off = 128; off > 0; off >>= 1) {
        if (t < off) red[t] += red[t + off];
        __syncthreads();
    }
    float inv = 1.0f / red[0];
#pragma unroll
    for (int i = 0; i < 8; i++) row[t + i * 256] = v[i] * inv;
}

// ---------------------------------------------------------------- U[b,hp,c] = sum_s attn[b,hp,s]*hidden[b,s,c]
__global__ void U_kernel(const float* __restrict__ attn,
                         const float* __restrict__ hidden,
                         float* __restrict__ U) {
    int b = blockIdx.x;
    int mt = blockIdx.y >> 4, nt = blockIdx.y & 15;
    __shared__ float Ash[64][33]; // attn [hp][s-chunk]
    __shared__ float Bsh[32][65]; // hidden [s-chunk][c]
    int tid = threadIdx.x, tx = tid & 15, ty = tid >> 4;
    float acc[4][4] = {};
    for (int k0 = 0; k0 < Sn; k0 += 32) {
        {
            int r = tid >> 2, cc = (tid & 3) * 8;
            const float* src = &attn[((size_t)b * 128 + mt * 64 + r) * Sn + k0 + cc];
#pragma unroll
            for (int i = 0; i < 8; i++) Ash[r][cc + i] = src[i];
        }
        {
            int r2 = tid >> 3, cc2 = (tid & 7) * 8;
            const float* src = &hidden[((size_t)b * Sn + k0 + r2) * Dn + nt * 64 + cc2];
#pragma unroll
            for (int i = 0; i < 8; i++) Bsh[r2][cc2 + i] = src[i];
        }
        __syncthreads();
#pragma unroll
        for (int kk = 0; kk < 32; kk++) {
            float a[4], bb[4];
#pragma unroll
            for (int i = 0; i < 4; i++) a[i] = Ash[ty * 4 + i][kk];
#pragma unroll
            for (int j = 0; j < 4; j++) bb[j] = Bsh[kk][tx * 4 + j];
#pragma unroll
            for (int i = 0; i < 4; i++)
#pragma unroll
                for (int j = 0; j < 4; j++)
                    acc[i][j] = fmaf(a[i], bb[j], acc[i][j]);
        }
        __syncthreads();
    }
#pragma unroll
    for (int i = 0; i < 4; i++)
#pragma unroll
        for (int j = 0; j < 4; j++)
            U[((size_t)b * 128 + mt * 64 + ty * 4 + i) * Dn + nt * 64 + tx * 4 + j] = acc[i][j];
}

// ---------------------------------------------------------------- ctx[bp, h*64+d] = U[b,h*8+p,:] . Wv[h*64+d,:] + bv
__global__ void ctx_kernel(const float* __restrict__ U,
                           const float* __restrict__ in_w,
                           const float* __restrict__ in_b,
                           float* __restrict__ ctx) {
    int h = blockIdx.x, mt = blockIdx.y;
    __shared__ float Ash[64][33];
    __shared__ float Bsh[64][33];
    int tid = threadIdx.x, tx = tid & 15, ty = tid >> 4;
    float acc[4][4] = {};
    for (int k0 = 0; k0 < Dn; k0 += 32) {
        int r = tid >> 2, cc = (tid & 3) * 8;
        {
            int bp = mt * 64 + r;
            int bb = bp >> 3, p = bp & 7;
            const float* src = &U[((size_t)bb * 128 + h * 8 + p) * Dn + k0 + cc];
#pragma unroll
            for (int i = 0; i < 8; i++) Ash[r][cc + i] = src[i];
        }
        {
            const float* src = &in_w[(size_t)(2 * Dn + h * 64 + r) * Dn + k0 + cc];
#pragma unroll
            for (int i = 0; i < 8; i++) Bsh[r][cc + i] = src[i];
        }
        __syncthreads();
#pragma unroll
        for (int kk = 0; kk < 32; kk++) {
            float a[4], bb[4];
#pragma unroll
            for (int i = 0; i < 4; i++) a[i] = Ash[ty * 4 + i][kk];
#pragma unroll
            for (int j = 0; j < 4; j++) bb[j] = Bsh[tx * 4 + j][kk];
#pragma unroll
            for (int i = 0; i < 4; i++)
#pragma unroll
                for (int j = 0; j < 4; j++)
                    acc[i][j] = fmaf(a[i], bb[j], acc[i][j]);
        }
        __syncthreads();
    }
#pragma unroll
    for (int i = 0; i < 4; i++) {
        int bp = mt * 64 + ty * 4 + i;
#pragma unroll
        for (int j = 0; j < 4; j++) {
            int d = tx * 4 + j;
            ctx[(size_t)bp * Dn + h * 64 + d] = acc[i][j] + in_b[2 * Dn + h * 64 + d];
        }
    }
}

// ---------------------------------------------------------------- generic C[M,N] = A[M,K] @ B[N,K]^T + bias
__global__ void gemm_abT(const float* __restrict__ A, const float* __restrict__ B,
                         const float* __restrict__ bias, float* __restrict__ C,
                         int M, int N, int K) {
    __shared__ float Ash[64][33];
    __shared__ float Bsh[64][33];
    int m0 = blockIdx.x * 64, n0 = blockIdx.y * 64;
    int tid = threadIdx.x, tx = tid & 15, ty = tid >> 4;
    float acc[4][4] = {};
    for (int k0 = 0; k0 < K; k0 += 32) {
        int r = tid >> 2, cc = (tid & 3) * 8;
        {
            int row = m0 + r;
            int rs = (row < M) ? row : (M - 1);
            bool ok = row < M;
            const float* src = &A[(size_t)rs * K + k0 + cc];
#pragma unroll
            for (int i = 0; i < 8; i++) Ash[r][cc + i] = ok ? src[i] : 0.0f;
        }
        {
            const float* src = &B[(size_t)(n0 + r) * K + k0 + cc];
#pragma unroll
            for (int i = 0; i < 8; i++) Bsh[r][cc + i] = src[i];
        }
        __syncthreads();
#pragma unroll
        for (int kk = 0; kk < 32; kk++) {
            float a[4], bb[4];
#pragma unroll
            for (int i = 0; i < 4; i++) a[i] = Ash[ty * 4 + i][kk];
#pragma unroll
            for (int j = 0; j < 4; j++) bb[j] = Bsh[tx * 4 + j][kk];
#pragma unroll
            for (int i = 0; i < 4; i++)
#pragma unroll
                for (int j = 0; j < 4; j++)
                    acc[i][j] = fmaf(a[i], bb[j], acc[i][j]);
        }
        __syncthreads();
    }
#pragma unroll
    for (int i = 0; i < 4; i++) {
        int row = m0 + ty * 4 + i;
        if (row < M) {
#pragma unroll
            for (int j = 0; j < 4; j++) {
                int col = n0 + tx * 4 + j;
                C[(size_t)row * N + col] = acc[i][j] + bias[col];
            }
        }
    }
}

// ---------------------------------------------------------------- block sum helper
__device__ __forceinline__ float block_sum(float v, float* red) {
    int tid = threadIdx.x;
    red[tid] = v;
    __syncthreads();
    for (int off = 128; off > 0; off >>= 1) {
        if (tid < off) red[tid] += red[tid + off];
        __syncthreads();
    }
    float r = red[0];
    __syncthreads();
    return r;
}

// ---------------------------------------------------------------- build summary row + LN_pma (pma rows) + LN_v / LN_g
__global__ void summary_ln_kernel(const float* __restrict__ hidden,
                                  const float* __restrict__ queries,
                                  const float* __restrict__ pooled,
                                  const int* __restrict__ rsrc,
                                  const float* __restrict__ gpma, const float* __restrict__ bpma,
                                  const float* __restrict__ gv, const float* __restrict__ bv,
                                  const float* __restrict__ gg, const float* __restrict__ bg,
                                  float* __restrict__ lnv, float* __restrict__ lng) {
    __shared__ float red[256];
    int b = blockIdx.x, t = blockIdx.y, tid = threadIdx.x;
    float x[4];
    if (t == 0) {
#pragma unroll
        for (int i = 0; i < 4; i++)
            x[i] = hidden[(size_t)b * Sn * Dn + tid + i * 256];
    } else if (t < 1 + Pn) {
        int p = t - 1;
#pragma unroll
        for (int i = 0; i < 4; i++) {
            int c = tid + i * 256;
            x[i] = queries[p * Dn + c] + pooled[((size_t)b * Pn + p) * Dn + c];
        }
    } else {
        int src = rsrc[b * RECn + (t - 9)];
        if (src >= 0) {
#pragma unroll
            for (int i = 0; i < 4; i++)
                x[i] = hidden[((size_t)b * Sn + src) * Dn + tid + i * 256];
        } else {
#pragma unroll
            for (int i = 0; i < 4; i++) x[i] = 0.0f;
        }
    }
    if (t >= 1 && t < 1 + Pn) {
        float mu = block_sum(x[0] + x[1] + x[2] + x[3], red) * (1.0f / Dn);
        float d2 = 0.0f;
#pragma unroll
        for (int i = 0; i < 4; i++) { float d = x[i] - mu; d2 += d * d; }
        float inv = rsqrtf(block_sum(d2, red) * (1.0f / Dn) + 1e-5f);
#pragma unroll
        for (int i = 0; i < 4; i++) {
            int c = tid + i * 256;
            x[i] = (x[i] - mu) * inv * gpma[c] + bpma[c];
        }
    }
    float mu = block_sum(x[0] + x[1] + x[2] + x[3], red) * (1.0f / Dn);
    float d2 = 0.0f;
#pragma unroll
    for (int i = 0; i < 4; i++) { float d = x[i] - mu; d2 += d * d; }
    float inv = rsqrtf(block_sum(d2, red) * (1.0f / Dn) + 1e-5f);
    size_t row = (size_t)(b * Tn + t) * Dn;
#pragma unroll
    for (int i = 0; i < 4; i++) {
        int c = tid + i * 256;
        float xh = (x[i] - mu) * inv;
        lnv[row + c] = xh * gv[c] + bv[c];
        lng[row + c] = xh * gg[c] + bg[c];
    }
}

// ---------------------------------------------------------------- gated = sigmoid(c2) * silu(c1) * mask
__global__ void gated_kernel(const float* __restrict__ c1, const float* __restrict__ c2,
                             const float* __restrict__ maskf, float* __restrict__ out) {
    int gi = blockIdx.x * blockDim.x + threadIdx.x;
    int row = gi >> 10;
    float m = maskf[row];
    float a = c1[gi], g = c2[gi];
    float sv = a / (1.0f + expf(-a));
    float sg = 1.0f / (1.0f + expf(-g));
    out[gi] = sg * sv * m;
}

// ================================================================ launch
extern "C" void kernel_launch(void* const* d_in, const int* in_sizes, int n_in,
                              void* d_out, int out_size, void* d_ws, size_t ws_size,
                              hipStream_t stream) {
    const float* hidden = (const float*)d_in[0];
    const void* valid_raw = d_in[1];
    const float* queries = (const float*)d_in[2];
    const float* in_w = (const float*)d_in[3];
    const float* in_b = (const float*)d_in[4];
    const float* out_w = (const float*)d_in[5];
    const float* out_b = (const float*)d_in[6];
    const float* ln_pma_g = (const float*)d_in[7];
    const float* ln_pma_b = (const float*)d_in[8];
    const float* ln_v_g = (const float*)d_in[9];
    const float* ln_v_b = (const float*)d_in[10];
    const float* W_v = (const float*)d_in[11];
    const float* b_v = (const float*)d_in[12];
    const float* ln_g_g = (const float*)d_in[13];
    const float* ln_g_b = (const float*)d_in[14];
    const float* W_g = (const float*)d_in[15];
    const float* b_g = (const float*)d_in[16];

    float* ws = (float*)d_ws;
    float* out = (float*)d_out;

    // workspace layout (floats), with overlays:
    float* SC = ws;                          // scores/attn: 16*128*2048 = 4194304
    float* Uw = ws + 4194304;                // U: 16*128*1024 = 2097152  -> ends 6291456
    float* qbuf = ws + 6291456;              // 8192
    float* Amat = qbuf + 8192;               // 131072
    float* c0 = Amat + 131072;               // 128 (pad to 1024)
    float* ctx = c0 + 1024;                  // 131072
    float* pooled = ctx + 131072;            // 131072 -> ends 6694016 floats
    // post-attention overlays (SC and Uw dead by the time these are written):
    float* lnv = ws;                         // 1168*1024 = 1196032
    float* lng = lnv + 1196032;
    float* c1 = lng + 1196032;
    float* c2 = c1 + 1196032;                // ends 4784128 < 6291456 (U region, dead)
    int* ivals = (int*)(ws + 6694016);
    int* totals = ivals;                     // 16
    int* rsrc = ivals + 16;                  // 1024
    int* flag = ivals + 16 + 1024;           // 1 (pad to 16)
    unsigned char* canon = (unsigned char*)(ivals + 16 + 1024 + 16); // 32768 bytes
    float* maskf = out + (size_t)Bn * Tn * Dn;

    detect_mask_kernel<<<1, 256, 0, stream>>>((const unsigned char*)valid_raw, flag);
    canon_mask_kernel<<<(Bn * Sn) / 256, 256, 0, stream>>>(valid_raw, flag, canon);
    prep_kernel<<<Bn, 256, 0, stream>>>(canon, totals, rsrc, maskf);
    q_kernel<<<(Pn * Dn) / 4, 256, 0, stream>>>(queries, in_w, in_b, qbuf);
    A_kernel<<<128, 256, 0, stream>>>(qbuf, in_w, in_b, Amat, c0);
    scores_kernel<<<dim3((Bn * Sn) / 64, 2), 256, 0, stream>>>(hidden, Amat, c0, canon, SC);
    softmax_kernel<<<Bn * 128, 256, 0, stream>>>(SC);
    U_kernel<<<dim3(Bn, 32), 256, 0, stream>>>(SC, hidden, Uw);
    ctx_kernel<<<dim3(Hn, 2), 256, 0, stream>>>(Uw, in_w, in_b, ctx);
    gemm_abT<<<dim3(2, 16), 256, 0, stream>>>(ctx, out_w, out_b, pooled, Bn * Pn, Dn, Dn);
    summary_ln_kernel<<<dim3(Bn, Tn), 256, 0, stream>>>(hidden, queries, pooled, rsrc,
                                                        ln_pma_g, ln_pma_b, ln_v_g, ln_v_b,
                                                        ln_g_g, ln_g_b, lnv, lng);
    gemm_abT<<<dim3((Bn * Tn + 63) / 64, 16), 256, 0, stream>>>(lnv, W_v, b_v, c1, Bn * Tn, Dn, Dn);
    gemm_abT<<<dim3((Bn * Tn + 63) / 64, 16), 256, 0, stream>>>(lng, W_g, b_g, c2, Bn * Tn, Dn, Dn);
    gated_kernel<<<(Bn * Tn * Dn) / 256, 256, 0, stream>>>(c1, c2, maskf, out);
}

// Round 3
// 489.669 us; speedup vs baseline: 1.7083x; 1.7083x over previous
//
#include <hip/hip_runtime.h>
#include <math.h>

// Dims fixed by setup_inputs(): B=16, S=2048, D=1024, H=16, hd=64, P=8,
// cls=1, pma=8, recent=64, T=73.

#define Bn 16
#define Sn 2048
#define Dn 1024
#define Hn 16
#define Pn 8
#define Tn 73
#define RECn 64

typedef __attribute__((ext_vector_type(8))) short short8;
typedef __attribute__((ext_vector_type(4))) float f32x4;

__device__ __forceinline__ short f2bf(float x) {
    unsigned u = __float_as_uint(x);
    u += 0x7fffu + ((u >> 16) & 1u);   // round-to-nearest-even; no NaN inputs here
    return (short)(u >> 16);
}

// ---------------------------------------------------------------- mask dtype detect
__global__ void detect_mask_kernel(const unsigned char* __restrict__ raw,
                                   int* __restrict__ flag) {
    __shared__ int any;
    if (threadIdx.x == 0) any = 0;
    __syncthreads();
    int local = 0;
    for (int i = threadIdx.x; i < Bn * Sn; i += blockDim.x)
        if ((i & 3) && raw[i]) local = 1;
    if (local) any = 1; // benign race
    __syncthreads();
    if (threadIdx.x == 0) *flag = any;
}

__global__ void canon_mask_kernel(const void* __restrict__ raw,
                                  const int* __restrict__ flag,
                                  unsigned char* __restrict__ canon) {
    int i = blockIdx.x * blockDim.x + threadIdx.x;
    if (i >= Bn * Sn) return;
    unsigned char v;
    if (*flag)
        v = ((const unsigned char*)raw)[i] ? 1 : 0;
    else
        v = ((const int*)raw)[i] ? 1 : 0;
    canon[i] = v;
}

// ---------------------------------------------------------------- prep
__global__ void prep_kernel(const unsigned char* __restrict__ valid,
                            int* __restrict__ totals, int* __restrict__ rsrc,
                            float* __restrict__ maskf) {
    int b = blockIdx.x, t = threadIdx.x;
    const int SP = Sn - 1; // 2047
    __shared__ int lc[256];
    if (t < RECn) rsrc[b * RECn + t] = -1;

    int base = t * 8;
    unsigned char m[8];
    int cnt = 0;
#pragma unroll
    for (int i = 0; i < 8; i++) {
        int idx = base + i;
        m[i] = (idx < SP) ? valid[(size_t)b * Sn + 1 + idx] : (unsigned char)0;
        cnt += m[i] ? 1 : 0;
    }
    lc[t] = cnt;
    __syncthreads();
    for (int off = 1; off < 256; off <<= 1) {
        int add = (t >= off) ? lc[t - off] : 0;
        __syncthreads();
        lc[t] += add;
        __syncthreads();
    }
    int total = lc[255];
    int run = lc[t] - cnt; // exclusive prefix
#pragma unroll
    for (int i = 0; i < 8; i++) {
        if (m[i]) {
            run++;
            int rank = total - run;
            if (rank < RECn) rsrc[b * RECn + (RECn - 1 - rank)] = base + i + 1;
        }
    }
    if (t == 0) totals[b] = total;
    if (t < Tn) {
        float mv;
        if (t == 0) mv = valid[(size_t)b * Sn] ? 1.0f : 0.0f;
        else if (t < 1 + Pn) mv = 1.0f;
        else mv = ((t - 9) >= RECn - total) ? 1.0f : 0.0f;
        maskf[b * Tn + t] = mv;
    }
}

// ---------------------------------------------------------------- q = queries @ Wq^T + bq
__global__ void q_kernel(const float* __restrict__ queries,
                         const float* __restrict__ in_w,
                         const float* __restrict__ in_b,
                         float* __restrict__ q) {
    int wid = (blockIdx.x * blockDim.x + threadIdx.x) >> 6;
    int lane = threadIdx.x & 63;
    if (wid >= Pn * Dn) return;
    int p = wid >> 10, j = wid & 1023;
    float acc = 0.0f;
    for (int c = lane; c < Dn; c += 64)
        acc += queries[p * Dn + c] * in_w[(size_t)j * Dn + c];
#pragma unroll
    for (int off = 32; off > 0; off >>= 1) acc += __shfl_down(acc, off);
    if (lane == 0) q[wid] = acc + in_b[j];
}

// ---------------------------------------------------------------- A_bf[hp,c] = bf16((q_h[p] . Wk_h[:,c]) / 8) ; c0[hp] = (q_h[p] . bk_h)/8
__global__ void A_kernel(const float* __restrict__ q,
                         const float* __restrict__ in_w,
                         const float* __restrict__ in_b,
                         short* __restrict__ Amat_bf, float* __restrict__ c0) {
    int hp = blockIdx.x;
    int h = hp >> 3, p = hp & 7;
    __shared__ float qs[64];
    if (threadIdx.x < 64) qs[threadIdx.x] = q[p * Dn + h * 64 + threadIdx.x];
    __syncthreads();
    for (int c = threadIdx.x; c < Dn; c += blockDim.x) {
        float acc = 0.0f;
#pragma unroll
        for (int d = 0; d < 64; d++)
            acc += qs[d] * in_w[(size_t)(Dn + h * 64 + d) * Dn + c];
        Amat_bf[(size_t)hp * Dn + c] = f2bf(acc * 0.125f);
    }
    if (threadIdx.x == 0) {
        float acc = 0.0f;
        for (int d = 0; d < 64; d++) acc += qs[d] * in_b[Dn + h * 64 + d];
        c0[hp] = acc * 0.125f;
    }
}

// ---------------------------------------------------------------- f32 -> bf16 elementwise (weights)
__global__ void wcvt_kernel(const float* __restrict__ w, short* __restrict__ wbf, int n) {
    int i = (blockIdx.x * blockDim.x + threadIdx.x) * 8;
    if (i >= n) return;
    f32x4 x0 = *(const f32x4*)(w + i);
    f32x4 x1 = *(const f32x4*)(w + i + 4);
    short8 o;
#pragma unroll
    for (int j = 0; j < 4; j++) { o[j] = f2bf(x0[j]); o[j + 4] = f2bf(x1[j]); }
    *(short8*)(wbf + i) = o;
}

// ---------------------------------------------------------------- scores[b,hp,s] = hidden[b,s,:]@A[hp,:] + c0 (MFMA bf16), masked
// grid: 512 blocks (each 64 s-rows), 4 waves: wave w owns rows m0 = blk*64+w*16.
// Wave computes 16(s) x 128(hp): A-frag from f32 hidden (cvt in-reg), B-frags from Amat_bf.
__global__ __launch_bounds__(256) void scores_mfma(const float* __restrict__ hidden,
                                                   const short* __restrict__ Amat_bf,
                                                   const float* __restrict__ c0,
                                                   const unsigned char* __restrict__ valid,
                                                   float* __restrict__ scores) {
    int wave = threadIdx.x >> 6, lane = threadIdx.x & 63;
    int m0 = blockIdx.x * 64 + wave * 16;      // row in [0, 32768)
    int b = m0 >> 11, s_base = m0 & 2047;
    int koff = (lane >> 4) * 8;
    const float* aptr = hidden + (size_t)(m0 + (lane & 15)) * Dn + koff;
    f32x4 acc[8] = {};
    for (int k0 = 0; k0 < Dn; k0 += 32) {
        f32x4 a0 = *(const f32x4*)(aptr + k0);
        f32x4 a1 = *(const f32x4*)(aptr + k0 + 4);
        short8 av;
#pragma unroll
        for (int i = 0; i < 4; i++) { av[i] = f2bf(a0[i]); av[i + 4] = f2bf(a1[i]); }
#pragma unroll
        for (int nt = 0; nt < 8; nt++) {
            short8 bv = *(const short8*)(Amat_bf + (size_t)(nt * 16 + (lane & 15)) * Dn + k0 + koff);
            acc[nt] = __builtin_amdgcn_mfma_f32_16x16x32_bf16(av, bv, acc[nt], 0, 0, 0);
        }
    }
    // epilogue: C/D layout col=lane&15 (hp), row=(lane>>4)*4+reg (s)
    int srow = s_base + (lane >> 4) * 4;
    const unsigned char* vptr = valid + (size_t)b * Sn + srow;
    bool ok0 = vptr[0] != 0, ok1 = vptr[1] != 0, ok2 = vptr[2] != 0, ok3 = vptr[3] != 0;
#pragma unroll
    for (int nt = 0; nt < 8; nt++) {
        int hp = nt * 16 + (lane & 15);
        float cc = c0[hp];
        f32x4 st;
        st[0] = ok0 ? acc[nt][0] + cc : -1.0e9f;
        st[1] = ok1 ? acc[nt][1] + cc : -1.0e9f;
        st[2] = ok2 ? acc[nt][2] + cc : -1.0e9f;
        st[3] = ok3 ? acc[nt][3] + cc : -1.0e9f;
        *(f32x4*)(scores + (size_t)(b * 128 + hp) * Sn + srow) = st;
    }
}

// ---------------------------------------------------------------- softmax over s; writes bf16 attn
__global__ __launch_bounds__(256) void softmax_kernel(const float* __restrict__ scores,
                                                      short* __restrict__ attn_bf) {
    const float* row = scores + (size_t)blockIdx.x * Sn;
    short* orow = attn_bf + (size_t)blockIdx.x * Sn;
    int t = threadIdx.x;
    __shared__ float red[256];
    f32x4 v0 = *(const f32x4*)(row + t * 8);
    f32x4 v1 = *(const f32x4*)(row + t * 8 + 4);
    float mx = -1.0e30f;
#pragma unroll
    for (int i = 0; i < 4; i++) { mx = fmaxf(mx, v0[i]); mx = fmaxf(mx, v1[i]); }
    red[t] = mx;
    __syncthreads();
    for (int off = 128; off > 0; off >>= 1) {
        if (t < off) red[t] = fmaxf(red[t], red[t + off]);
        __syncthreads();
    }
    mx = red[0];
    __syncthreads();
    float e[8];
    float sum = 0.0f;
#pragma unroll
    for (int i = 0; i < 4; i++) {
        e[i] = expf(v0[i] - mx); sum += e[i];
        e[i + 4] = expf(v1[i] - mx); sum += e[i + 4];
    }
    red[t] = sum;
    __syncthreads();
    for (int off = 128; off > 0; off >>= 1) {
        if (t < off) red[t] += red[t + off];
        __syncthreads();
    }
    float inv = 1.0f / red[0];
    short8 o;
#pragma unroll
    for (int i = 0; i < 8; i++) o[i] = f2bf(e[i] * inv);
    *(short8*)(orow + t * 8) = o;
}

// ---------------------------------------------------------------- U[b,hp,c] = attn[b,hp,:] @ hidden[b,:,c]  (MFMA bf16)
// grid (16 n-tiles, 16 b); block 256 = 4 waves; block tile 128(hp) x 64(c).
// B staged through LDS transposed to [n][k] bf16 (pitch 40 shorts -> 16B-aligned b128 reads).
__global__ __launch_bounds__(256) void U_mfma(const short* __restrict__ attn_bf,
                                              const float* __restrict__ hidden,
                                              float* __restrict__ U) {
    int b = blockIdx.y, n0 = blockIdx.x * 64;
    int tid = threadIdx.x, wave = tid >> 6, lane = tid & 63;
    __shared__ short ldsB[64][40];
    int kr = tid & 31, nc = (tid >> 5) * 8;
    int koff = (lane >> 4) * 8;
    f32x4 acc[2][4] = {};
    const short* aBase = attn_bf + ((size_t)b * 128 + wave * 32 + (lane & 15)) * Sn + koff;
    const float* hBase = hidden + ((size_t)b * Sn + kr) * Dn + n0 + nc;
    for (int k0 = 0; k0 < Sn; k0 += 32) {
        f32x4 h0 = *(const f32x4*)(hBase + (size_t)k0 * Dn);
        f32x4 h1 = *(const f32x4*)(hBase + (size_t)k0 * Dn + 4);
        __syncthreads();   // previous iteration's ds_reads done
#pragma unroll
        for (int i = 0; i < 4; i++) {
            ldsB[nc + i][kr] = f2bf(h0[i]);
            ldsB[nc + 4 + i][kr] = f2bf(h1[i]);
        }
        __syncthreads();
        short8 av0 = *(const short8*)(aBase + k0);
        short8 av1 = *(const short8*)(aBase + (size_t)16 * Sn + k0);
#pragma unroll
        for (int nf = 0; nf < 4; nf++) {
            short8 bv = *(const short8*)(&ldsB[nf * 16 + (lane & 15)][koff]);
            acc[0][nf] = __builtin_amdgcn_mfma_f32_16x16x32_bf16(av0, bv, acc[0][nf], 0, 0, 0);
            acc[1][nf] = __builtin_amdgcn_mfma_f32_16x16x32_bf16(av1, bv, acc[1][nf], 0, 0, 0);
        }
    }
#pragma unroll
    for (int mf = 0; mf < 2; mf++) {
        int hp = wave * 32 + mf * 16 + (lane >> 4) * 4;
#pragma unroll
        for (int nf = 0; nf < 4; nf++) {
            int c = n0 + nf * 16 + (lane & 15);
            float* up = U + (size_t)(b * 128 + hp) * Dn + c;
#pragma unroll
            for (int r = 0; r < 4; r++) up[(size_t)r * Dn] = acc[mf][nf][r];
        }
    }
}

// ---------------------------------------------------------------- ctx[bp, h*64+d] = U[b,h*8+p,:] . Wv[h*64+d,:] + bv  (f32, small)
__global__ void ctx_kernel(const float* __restrict__ U,
                           const float* __restrict__ in_w,
                           const float* __restrict__ in_b,
                           float* __restrict__ ctx) {
    int h = blockIdx.x, mt = blockIdx.y;
    __shared__ float Ash[64][33];
    __shared__ float Bsh[64][33];
    int tid = threadIdx.x, tx = tid & 15, ty = tid >> 4;
    float acc[4][4] = {};
    for (int k0 = 0; k0 < Dn; k0 += 32) {
        int r = tid >> 2, cc = (tid & 3) * 8;
        {
            int bp = mt * 64 + r;
            int bb = bp >> 3, p = bp & 7;
            const float* src = &U[((size_t)bb * 128 + h * 8 + p) * Dn + k0 + cc];
#pragma unroll
            for (int i = 0; i < 8; i++) Ash[r][cc + i] = src[i];
        }
        {
            const float* src = &in_w[(size_t)(2 * Dn + h * 64 + r) * Dn + k0 + cc];
#pragma unroll
            for (int i = 0; i < 8; i++) Bsh[r][cc + i] = src[i];
        }
        __syncthreads();
#pragma unroll
        for (int kk = 0; kk < 32; kk++) {
            float a[4], bb2[4];
#pragma unroll
            for (int i = 0; i < 4; i++) a[i] = Ash[ty * 4 + i][kk];
#pragma unroll
            for (int j = 0; j < 4; j++) bb2[j] = Bsh[tx * 4 + j][kk];
#pragma unroll
            for (int i = 0; i < 4; i++)
#pragma unroll
                for (int j = 0; j < 4; j++)
                    acc[i][j] = fmaf(a[i], bb2[j], acc[i][j]);
        }
        __syncthreads();
    }
#pragma unroll
    for (int i = 0; i < 4; i++) {
        int bp = mt * 64 + ty * 4 + i;
#pragma unroll
        for (int j = 0; j < 4; j++) {
            int d = tx * 4 + j;
            ctx[(size_t)bp * Dn + h * 64 + d] = acc[i][j] + in_b[2 * Dn + h * 64 + d];
        }
    }
}

// ---------------------------------------------------------------- generic f32 C[M,N] = A[M,K] @ B[N,K]^T + bias (small GEMMs)
__global__ void gemm_abT(const float* __restrict__ A, const float* __restrict__ B,
                         const float* __restrict__ bias, float* __restrict__ C,
                         int M, int N, int K) {
    __shared__ float Ash[64][33];
    __shared__ float Bsh[64][33];
    int m0 = blockIdx.x * 64, n0 = blockIdx.y * 64;
    int tid = threadIdx.x, tx = tid & 15, ty = tid >> 4;
    float acc[4][4] = {};
    for (int k0 = 0; k0 < K; k0 += 32) {
        int r = tid >> 2, cc = (tid & 3) * 8;
        {
            int row = m0 + r;
            int rs = (row < M) ? row : (M - 1);
            bool ok = row < M;
            const float* src = &A[(size_t)rs * K + k0 + cc];
#pragma unroll
            for (int i = 0; i < 8; i++) Ash[r][cc + i] = ok ? src[i] : 0.0f;
        }
        {
            const float* src = &B[(size_t)(n0 + r) * K + k0 + cc];
#pragma unroll
            for (int i = 0; i < 8; i++) Bsh[r][cc + i] = src[i];
        }
        __syncthreads();
#pragma unroll
        for (int kk = 0; kk < 32; kk++) {
            float a[4], bb[4];
#pragma unroll
            for (int i = 0; i < 4; i++) a[i] = Ash[ty * 4 + i][kk];
#pragma unroll
            for (int j = 0; j < 4; j++) bb[j] = Bsh[tx * 4 + j][kk];
#pragma unroll
            for (int i = 0; i < 4; i++)
#pragma unroll
                for (int j = 0; j < 4; j++)
                    acc[i][j] = fmaf(a[i], bb[j], acc[i][j]);
        }
        __syncthreads();
    }
#pragma unroll
    for (int i = 0; i < 4; i++) {
        int row = m0 + ty * 4 + i;
        if (row < M) {
#pragma unroll
            for (int j = 0; j < 4; j++) {
                int col = n0 + tx * 4 + j;
                C[(size_t)row * N + col] = acc[i][j] + bias[col];
            }
        }
    }
}

// ---------------------------------------------------------------- bf16 MFMA GEMM: C[M,1024] = A_bf[M,1024] @ B_bf[1024,1024]^T + bias
__global__ __launch_bounds__(256) void wgemm_mfma(const short* __restrict__ Abf,
                                                  const short* __restrict__ Bbf,
                                                  const float* __restrict__ bias,
                                                  float* __restrict__ C, int M) {
    int wave = threadIdx.x >> 6, lane = threadIdx.x & 63;
    int m0 = blockIdx.x * 64 + (wave >> 1) * 32;
    int n0 = blockIdx.y * 64 + (wave & 1) * 32;
    int koff = (lane >> 4) * 8;
    f32x4 acc[2][2] = {};
    int ra0 = min(m0 + (lane & 15), M - 1);
    int ra1 = min(m0 + 16 + (lane & 15), M - 1);
    const short* a0p = Abf + (size_t)ra0 * Dn + koff;
    const short* a1p = Abf + (size_t)ra1 * Dn + koff;
    const short* b0p = Bbf + (size_t)(n0 + (lane & 15)) * Dn + koff;
    const short* b1p = Bbf + (size_t)(n0 + 16 + (lane & 15)) * Dn + koff;
    for (int k0 = 0; k0 < Dn; k0 += 32) {
        short8 av0 = *(const short8*)(a0p + k0);
        short8 av1 = *(const short8*)(a1p + k0);
        short8 bv0 = *(const short8*)(b0p + k0);
        short8 bv1 = *(const short8*)(b1p + k0);
        acc[0][0] = __builtin_amdgcn_mfma_f32_16x16x32_bf16(av0, bv0, acc[0][0], 0, 0, 0);
        acc[0][1] = __builtin_amdgcn_mfma_f32_16x16x32_bf16(av0, bv1, acc[0][1], 0, 0, 0);
        acc[1][0] = __builtin_amdgcn_mfma_f32_16x16x32_bf16(av1, bv0, acc[1][0], 0, 0, 0);
        acc[1][1] = __builtin_amdgcn_mfma_f32_16x16x32_bf16(av1, bv1, acc[1][1], 0, 0, 0);
    }
#pragma unroll
    for (int mf = 0; mf < 2; mf++) {
        int row0 = m0 + mf * 16 + (lane >> 4) * 4;
#pragma unroll
        for (int nf = 0; nf < 2; nf++) {
            int col = n0 + nf * 16 + (lane & 15);
            float bval = bias[col];
#pragma unroll
            for (int r = 0; r < 4; r++) {
                int row = row0 + r;
                if (row < M) C[(size_t)row * Dn + col] = acc[mf][nf][r] + bval;
            }
        }
    }
}

// ---------------------------------------------------------------- block sum helper
__device__ __forceinline__ float block_sum(float v, float* red) {
    int tid = threadIdx.x;
    red[tid] = v;
    __syncthreads();
    for (int off = 128; off > 0; off >>= 1) {
        if (tid < off) red[tid] += red[tid + off];
        __syncthreads();
    }
    float r = red[0];
    __syncthreads();
    return r;
}

// ---------------------------------------------------------------- build summary row + LN_pma + LN_v / LN_g (bf16 out)
__global__ void summary_ln_kernel(const float* __restrict__ hidden,
                                  const float* __restrict__ queries,
                                  const float* __restrict__ pooled,
                                  const int* __restrict__ rsrc,
                                  const float* __restrict__ gpma, const float* __restrict__ bpma,
                                  const float* __restrict__ gv, const float* __restrict__ bv,
                                  const float* __restrict__ gg, const float* __restrict__ bg,
                                  short* __restrict__ lnv, short* __restrict__ lng) {
    __shared__ float red[256];
    int b = blockIdx.x, t = blockIdx.y, tid = threadIdx.x;
    float x[4];
    if (t == 0) {
#pragma unroll
        for (int i = 0; i < 4; i++)
            x[i] = hidden[(size_t)b * Sn * Dn + tid + i * 256];
    } else if (t < 1 + Pn) {
        int p = t - 1;
#pragma unroll
        for (int i = 0; i < 4; i++) {
            int c = tid + i * 256;
            x[i] = queries[p * Dn + c] + pooled[((size_t)b * Pn + p) * Dn + c];
        }
    } else {
        int src = rsrc[b * RECn + (t - 9)];
        if (src >= 0) {
#pragma unroll
            for (int i = 0; i < 4; i++)
                x[i] = hidden[((size_t)b * Sn + src) * Dn + tid + i * 256];
        } else {
#pragma unroll
            for (int i = 0; i < 4; i++) x[i] = 0.0f;
        }
    }
    if (t >= 1 && t < 1 + Pn) {
        float mu = block_sum(x[0] + x[1] + x[2] + x[3], red) * (1.0f / Dn);
        float d2 = 0.0f;
#pragma unroll
        for (int i = 0; i < 4; i++) { float d = x[i] - mu; d2 += d * d; }
        float inv = rsqrtf(block_sum(d2, red) * (1.0f / Dn) + 1e-5f);
#pragma unroll
        for (int i = 0; i < 4; i++) {
            int c = tid + i * 256;
            x[i] = (x[i] - mu) * inv * gpma[c] + bpma[c];
        }
    }
    float mu = block_sum(x[0] + x[1] + x[2] + x[3], red) * (1.0f / Dn);
    float d2 = 0.0f;
#pragma unroll
    for (int i = 0; i < 4; i++) { float d = x[i] - mu; d2 += d * d; }
    float inv = rsqrtf(block_sum(d2, red) * (1.0f / Dn) + 1e-5f);
    size_t row = (size_t)(b * Tn + t) * Dn;
#pragma unroll
    for (int i = 0; i < 4; i++) {
        int c = tid + i * 256;
        float xh = (x[i] - mu) * inv;
        lnv[row + c] = f2bf(xh * gv[c] + bv[c]);
        lng[row + c] = f2bf(xh * gg[c] + bg[c]);
    }
}

// ---------------------------------------------------------------- gated = sigmoid(c2) * silu(c1) * mask
__global__ void gated_kernel(const float* __restrict__ c1, const float* __restrict__ c2,
                             const float* __restrict__ maskf, float* __restrict__ out) {
    int gi = blockIdx.x * blockDim.x + threadIdx.x;
    int row = gi >> 10;
    float m = maskf[row];
    float a = c1[gi], g = c2[gi];
    float sv = a / (1.0f + expf(-a));
    float sg = 1.0f / (1.0f + expf(-g));
    out[gi] = sg * sv * m;
}

// ================================================================ launch
extern "C" void kernel_launch(void* const* d_in, const int* in_sizes, int n_in,
                              void* d_out, int out_size, void* d_ws, size_t ws_size,
                              hipStream_t stream) {
    const float* hidden = (const float*)d_in[0];
    const void* valid_raw = d_in[1];
    const float* queries = (const float*)d_in[2];
    const float* in_w = (const float*)d_in[3];
    const float* in_b = (const float*)d_in[4];
    const float* out_w = (const float*)d_in[5];
    const float* out_b = (const float*)d_in[6];
    const float* ln_pma_g = (const float*)d_in[7];
    const float* ln_pma_b = (const float*)d_in[8];
    const float* ln_v_g = (const float*)d_in[9];
    const float* ln_v_b = (const float*)d_in[10];
    const float* W_v = (const float*)d_in[11];
    const float* b_v = (const float*)d_in[12];
    const float* ln_g_g = (const float*)d_in[13];
    const float* ln_g_b = (const float*)d_in[14];
    const float* W_g = (const float*)d_in[15];
    const float* b_g = (const float*)d_in[16];

    float* ws = (float*)d_ws;
    float* out = (float*)d_out;

    // workspace layout (float offsets):
    float* SC      = ws;                         // 16*128*2048       = 4,194,304 f
    short* attn_bf = (short*)(ws + 4194304);     // 4,194,304 shorts  = 2,097,152 f
    float* Uw      = ws + 6291456;               // 16*128*1024       = 2,097,152 f
    float* qbuf    = ws + 8388608;               // 8,192
    short* Amat_bf = (short*)(ws + 8396800);     // 128*1024 shorts   = 65,536 f
    float* c0      = ws + 8462336;               // 128 (pad 256)
    float* ctx     = ws + 8462592;               // 131,072
    float* pooled  = ws + 8593664;               // 131,072
    short* Wv_bf   = (short*)(ws + 8724736);     // 1024*1024 shorts  = 524,288 f
    short* Wg_bf   = (short*)(ws + 9249024);     // 524,288 f
    int*   ivals   = (int*)(ws + 9773312);
    int* totals = ivals;                         // 16
    int* rsrc = ivals + 16;                      // 1024
    int* flag = ivals + 16 + 1024;               // 16
    unsigned char* canon = (unsigned char*)(ivals + 16 + 1024 + 16); // 32768 B
    // overlays in SC region (SC dead after softmax):
    short* lnv_bf = (short*)ws;                  // 1168*1024 shorts = 598,016 f
    short* lng_bf = (short*)(ws + 622592);
    float* c1 = ws + 1245184;                    // 1,196,032
    float* c2 = ws + 2441216;                    // ends 3,637,248 < 4,194,304 OK
    float* maskf = out + (size_t)Bn * Tn * Dn;

    const int M2 = Bn * Tn; // 1168

    detect_mask_kernel<<<1, 256, 0, stream>>>((const unsigned char*)valid_raw, flag);
    canon_mask_kernel<<<(Bn * Sn) / 256, 256, 0, stream>>>(valid_raw, flag, canon);
    prep_kernel<<<Bn, 256, 0, stream>>>(canon, totals, rsrc, maskf);
    q_kernel<<<(Pn * Dn) / 4, 256, 0, stream>>>(queries, in_w, in_b, qbuf);
    A_kernel<<<128, 256, 0, stream>>>(qbuf, in_w, in_b, Amat_bf, c0);
    wcvt_kernel<<<512, 256, 0, stream>>>(W_v, Wv_bf, Dn * Dn);
    wcvt_kernel<<<512, 256, 0, stream>>>(W_g, Wg_bf, Dn * Dn);
    scores_mfma<<<(Bn * Sn) / 64, 256, 0, stream>>>(hidden, Amat_bf, c0, canon, SC);
    softmax_kernel<<<Bn * 128, 256, 0, stream>>>(SC, attn_bf);
    U_mfma<<<dim3(16, Bn), 256, 0, stream>>>(attn_bf, hidden, Uw);
    ctx_kernel<<<dim3(Hn, 2), 256, 0, stream>>>(Uw, in_w, in_b, ctx);
    gemm_abT<<<dim3(2, 16), 256, 0, stream>>>(ctx, out_w, out_b, pooled, Bn * Pn, Dn, Dn);
    summary_ln_kernel<<<dim3(Bn, Tn), 256, 0, stream>>>(hidden, queries, pooled, rsrc,
                                                        ln_pma_g, ln_pma_b, ln_v_g, ln_v_b,
                                                        ln_g_g, ln_g_b, lnv_bf, lng_bf);
    wgemm_mfma<<<dim3((M2 + 63) / 64, 16), 256, 0, stream>>>(lnv_bf, Wv_bf, b_v, c1, M2);
    wgemm_mfma<<<dim3((M2 + 63) / 64, 16), 256, 0, stream>>>(lng_bf, Wg_bf, b_g, c2, M2);
    gated_kernel<<<(Bn * Tn * Dn) / 256, 256, 0, stream>>>(c1, c2, maskf, out);
}

// Round 4
// 421.165 us; speedup vs baseline: 1.9861x; 1.1627x over previous
//
#include <hip/hip_runtime.h>
#include <math.h>

// Dims fixed by setup_inputs(): B=16, S=2048, D=1024, H=16, hd=64, P=8,
// cls=1, pma=8, recent=64, T=73.

#define Bn 16
#define Sn 2048
#define Dn 1024
#define Hn 16
#define Pn 8
#define Tn 73
#define RECn 64

typedef __attribute__((ext_vector_type(8))) short short8;
typedef __attribute__((ext_vector_type(4))) float f32x4;

__device__ __forceinline__ short f2bf(float x) {
    unsigned u = __float_as_uint(x);
    u += 0x7fffu + ((u >> 16) & 1u);   // round-to-nearest-even; no NaN inputs here
    return (short)(u >> 16);
}

// ---------------------------------------------------------------- mask dtype detect
__global__ void detect_mask_kernel(const unsigned char* __restrict__ raw,
                                   int* __restrict__ flag) {
    __shared__ int any;
    if (threadIdx.x == 0) any = 0;
    __syncthreads();
    const uint4* r4 = (const uint4*)raw;
    int local = 0;
    for (int i = threadIdx.x; i < (Bn * Sn) / 16; i += blockDim.x) {
        uint4 w = r4[i];
        if ((w.x & 0xFFFFFF00u) | (w.y & 0xFFFFFF00u) |
            (w.z & 0xFFFFFF00u) | (w.w & 0xFFFFFF00u)) local = 1;
    }
    if (local) any = 1; // benign race
    __syncthreads();
    if (threadIdx.x == 0) *flag = any;
}

__global__ void canon_mask_kernel(const void* __restrict__ raw,
                                  const int* __restrict__ flag,
                                  unsigned char* __restrict__ canon) {
    int i = blockIdx.x * blockDim.x + threadIdx.x;
    if (i >= Bn * Sn) return;
    unsigned char v;
    if (*flag)
        v = ((const unsigned char*)raw)[i] ? 1 : 0;
    else
        v = ((const int*)raw)[i] ? 1 : 0;
    canon[i] = v;
}

// ---------------------------------------------------------------- prep
__global__ void prep_kernel(const unsigned char* __restrict__ valid,
                            int* __restrict__ totals, int* __restrict__ rsrc,
                            float* __restrict__ maskf) {
    int b = blockIdx.x, t = threadIdx.x;
    const int SP = Sn - 1; // 2047
    __shared__ int lc[256];
    if (t < RECn) rsrc[b * RECn + t] = -1;

    int base = t * 8;
    unsigned char m[8];
    int cnt = 0;
#pragma unroll
    for (int i = 0; i < 8; i++) {
        int idx = base + i;
        m[i] = (idx < SP) ? valid[(size_t)b * Sn + 1 + idx] : (unsigned char)0;
        cnt += m[i] ? 1 : 0;
    }
    lc[t] = cnt;
    __syncthreads();
    for (int off = 1; off < 256; off <<= 1) {
        int add = (t >= off) ? lc[t - off] : 0;
        __syncthreads();
        lc[t] += add;
        __syncthreads();
    }
    int total = lc[255];
    int run = lc[t] - cnt; // exclusive prefix
#pragma unroll
    for (int i = 0; i < 8; i++) {
        if (m[i]) {
            run++;
            int rank = total - run;
            if (rank < RECn) rsrc[b * RECn + (RECn - 1 - rank)] = base + i + 1;
        }
    }
    if (t == 0) totals[b] = total;
    if (t < Tn) {
        float mv;
        if (t == 0) mv = valid[(size_t)b * Sn] ? 1.0f : 0.0f;
        else if (t < 1 + Pn) mv = 1.0f;
        else mv = ((t - 9) >= RECn - total) ? 1.0f : 0.0f;
        maskf[b * Tn + t] = mv;
    }
}

// ---------------------------------------------------------------- q = queries @ Wq^T + bq
__global__ void q_kernel(const float* __restrict__ queries,
                         const float* __restrict__ in_w,
                         const float* __restrict__ in_b,
                         float* __restrict__ q) {
    int wid = (blockIdx.x * blockDim.x + threadIdx.x) >> 6;
    int lane = threadIdx.x & 63;
    if (wid >= Pn * Dn) return;
    int p = wid >> 10, j = wid & 1023;
    float acc = 0.0f;
    for (int c = lane; c < Dn; c += 64)
        acc += queries[p * Dn + c] * in_w[(size_t)j * Dn + c];
#pragma unroll
    for (int off = 32; off > 0; off >>= 1) acc += __shfl_down(acc, off);
    if (lane == 0) q[wid] = acc + in_b[j];
}

// ---------------------------------------------------------------- A_bf[h*8+p,c] = bf16((q_h[p] . Wk_h[:,c]) / 8) ; c0
// grid (16 h, 4 cblk) x 256 threads; each weight element loaded once, used for all 8 p.
__global__ void A_kernel(const float* __restrict__ q,
                         const float* __restrict__ in_w,
                         const float* __restrict__ in_b,
                         short* __restrict__ Amat_bf, float* __restrict__ c0) {
    int h = blockIdx.x, cblk = blockIdx.y;
    int c = cblk * 256 + threadIdx.x;
    __shared__ float qs[8][64];
    for (int i = threadIdx.x; i < 512; i += 256) {
        int p = i >> 6, d = i & 63;
        qs[p][d] = q[p * Dn + h * 64 + d];
    }
    __syncthreads();
    float acc[8] = {};
#pragma unroll 8
    for (int d = 0; d < 64; d++) {
        float w = in_w[(size_t)(Dn + h * 64 + d) * Dn + c];
#pragma unroll
        for (int p = 0; p < 8; p++) acc[p] = fmaf(qs[p][d], w, acc[p]);
    }
#pragma unroll
    for (int p = 0; p < 8; p++)
        Amat_bf[(size_t)(h * 8 + p) * Dn + c] = f2bf(acc[p] * 0.125f);
    if (cblk == 0 && threadIdx.x < 8) {
        int p = threadIdx.x;
        float a = 0.0f;
        for (int d = 0; d < 64; d++) a += qs[p][d] * in_b[Dn + h * 64 + d];
        c0[h * 8 + p] = a * 0.125f;
    }
}

// ---------------------------------------------------------------- f32 -> bf16 elementwise (weights)
__global__ void wcvt_kernel(const float* __restrict__ w, short* __restrict__ wbf, int n) {
    int i = (blockIdx.x * blockDim.x + threadIdx.x) * 8;
    if (i >= n) return;
    f32x4 x0 = *(const f32x4*)(w + i);
    f32x4 x1 = *(const f32x4*)(w + i + 4);
    short8 o;
#pragma unroll
    for (int j = 0; j < 4; j++) { o[j] = f2bf(x0[j]); o[j + 4] = f2bf(x1[j]); }
    *(short8*)(wbf + i) = o;
}

// ---------------------------------------------------------------- scores[b,hp,s] = hidden[b,s,:]@A[hp,:] + c0 (MFMA bf16), masked
// 2048 blocks x 256 threads: block owns 16 s-rows; wave w owns hp tiles {2w, 2w+1}.
// All 4 waves read the same hidden rows (L1 hits); full occupancy (8 blocks/CU).
__global__ __launch_bounds__(256) void scores_mfma(const float* __restrict__ hidden,
                                                   const short* __restrict__ Amat_bf,
                                                   const float* __restrict__ c0,
                                                   const unsigned char* __restrict__ valid,
                                                   float* __restrict__ scores) {
    int wave = threadIdx.x >> 6, lane = threadIdx.x & 63;
    int m0 = blockIdx.x * 16;                  // row in [0, 32768)
    int b = m0 >> 11, s_base = m0 & 2047;
    int koff = (lane >> 4) * 8;
    const float* aptr = hidden + (size_t)(m0 + (lane & 15)) * Dn + koff;
    const short* b0p = Amat_bf + (size_t)(wave * 32 + (lane & 15)) * Dn + koff;
    const short* b1p = b0p + (size_t)16 * Dn;
    f32x4 acc[2] = {};
    for (int k0 = 0; k0 < Dn; k0 += 32) {
        f32x4 a0 = *(const f32x4*)(aptr + k0);
        f32x4 a1 = *(const f32x4*)(aptr + k0 + 4);
        short8 av;
#pragma unroll
        for (int i = 0; i < 4; i++) { av[i] = f2bf(a0[i]); av[i + 4] = f2bf(a1[i]); }
        short8 bv0 = *(const short8*)(b0p + k0);
        short8 bv1 = *(const short8*)(b1p + k0);
        acc[0] = __builtin_amdgcn_mfma_f32_16x16x32_bf16(av, bv0, acc[0], 0, 0, 0);
        acc[1] = __builtin_amdgcn_mfma_f32_16x16x32_bf16(av, bv1, acc[1], 0, 0, 0);
    }
    // epilogue: C/D layout col=lane&15 (hp within tile), row=(lane>>4)*4+reg (s)
    int srow = s_base + (lane >> 4) * 4;
    const unsigned char* vptr = valid + (size_t)b * Sn + srow;
    bool ok0 = vptr[0] != 0, ok1 = vptr[1] != 0, ok2 = vptr[2] != 0, ok3 = vptr[3] != 0;
#pragma unroll
    for (int t = 0; t < 2; t++) {
        int hp = wave * 32 + t * 16 + (lane & 15);
        float cc = c0[hp];
        f32x4 st;
        st[0] = ok0 ? acc[t][0] + cc : -1.0e9f;
        st[1] = ok1 ? acc[t][1] + cc : -1.0e9f;
        st[2] = ok2 ? acc[t][2] + cc : -1.0e9f;
        st[3] = ok3 ? acc[t][3] + cc : -1.0e9f;
        *(f32x4*)(scores + (size_t)(b * 128 + hp) * Sn + srow) = st;
    }
}

// ---------------------------------------------------------------- softmax over s; writes bf16 attn
__global__ __launch_bounds__(256) void softmax_kernel(const float* __restrict__ scores,
                                                      short* __restrict__ attn_bf) {
    const float* row = scores + (size_t)blockIdx.x * Sn;
    short* orow = attn_bf + (size_t)blockIdx.x * Sn;
    int t = threadIdx.x;
    __shared__ float red[256];
    f32x4 v0 = *(const f32x4*)(row + t * 8);
    f32x4 v1 = *(const f32x4*)(row + t * 8 + 4);
    float mx = -1.0e30f;
#pragma unroll
    for (int i = 0; i < 4; i++) { mx = fmaxf(mx, v0[i]); mx = fmaxf(mx, v1[i]); }
    red[t] = mx;
    __syncthreads();
    for (int off = 128; off > 0; off >>= 1) {
        if (t < off) red[t] = fmaxf(red[t], red[t + off]);
        __syncthreads();
    }
    mx = red[0];
    __syncthreads();
    float e[8];
    float sum = 0.0f;
#pragma unroll
    for (int i = 0; i < 4; i++) {
        e[i] = expf(v0[i] - mx); sum += e[i];
        e[i + 4] = expf(v1[i] - mx); sum += e[i + 4];
    }
    red[t] = sum;
    __syncthreads();
    for (int off = 128; off > 0; off >>= 1) {
        if (t < off) red[t] += red[t + off];
        __syncthreads();
    }
    float inv = 1.0f / red[0];
    short8 o;
#pragma unroll
    for (int i = 0; i < 8; i++) o[i] = f2bf(e[i] * inv);
    *(short8*)(orow + t * 8) = o;
}

// ---------------------------------------------------------------- U partials: Up[b,hp,c] = sum_{s in z-chunk} attn[b,hp,s]*hidden[b,s,c]
// grid (16 n-tiles, 16 b, 3 z) x 512 threads (8 waves). Tile 128(hp) x 64(c).
// hidden staged through LDS transposed to [c][k] bf16 (pitch 40).
__global__ __launch_bounds__(512) void U_mfma(const short* __restrict__ attn_bf,
                                              const float* __restrict__ hidden,
                                              float* __restrict__ Up0,
                                              float* __restrict__ Up1,
                                              float* __restrict__ Up2) {
    int b = blockIdx.y, n0 = blockIdx.x * 64, z = blockIdx.z;
    int zbase = z * 704;
    int zlen = (z == 2) ? 640 : 704;
    float* Up = (z == 0) ? Up0 : (z == 1) ? Up1 : Up2;

    int tid = threadIdx.x, wave = tid >> 6, lane = tid & 63;
    __shared__ short ldsB[64][40];
    int kr = tid & 31, nc = (tid >> 5) * 4;      // staging: thread -> (k=kr, c=nc..nc+3)
    int koff = (lane >> 4) * 8;
    f32x4 acc[4] = {};
    const short* aBase = attn_bf + ((size_t)b * 128 + wave * 16 + (lane & 15)) * Sn + zbase + koff;
    const float* hBase = hidden + ((size_t)b * Sn + zbase + kr) * Dn + n0 + nc;
    for (int k0 = 0; k0 < zlen; k0 += 32) {
        f32x4 h0 = *(const f32x4*)(hBase + (size_t)k0 * Dn);
        __syncthreads();   // previous iteration's ds_reads done
#pragma unroll
        for (int i = 0; i < 4; i++) ldsB[nc + i][kr] = f2bf(h0[i]);
        __syncthreads();
        short8 av = *(const short8*)(aBase + k0);
#pragma unroll
        for (int nf = 0; nf < 4; nf++) {
            short8 bv = *(const short8*)(&ldsB[nf * 16 + (lane & 15)][koff]);
            acc[nf] = __builtin_amdgcn_mfma_f32_16x16x32_bf16(av, bv, acc[nf], 0, 0, 0);
        }
    }
    int hp = wave * 16 + (lane >> 4) * 4;
#pragma unroll
    for (int nf = 0; nf < 4; nf++) {
        int c = n0 + nf * 16 + (lane & 15);
        float* up = Up + (size_t)(b * 128 + hp) * Dn + c;
#pragma unroll
        for (int r = 0; r < 4; r++) up[(size_t)r * Dn] = acc[nf][r];
    }
}

// ---------------------------------------------------------------- ctx[bp, h*64+d] = (Up0+Up1+Up2)[b,h*8+p,:] . Wv[h*64+d,:] + bv
__global__ void ctx_kernel(const float* __restrict__ Up0,
                           const float* __restrict__ Up1,
                           const float* __restrict__ Up2,
                           const float* __restrict__ in_w,
                           const float* __restrict__ in_b,
                           float* __restrict__ ctx) {
    int h = blockIdx.x, mt = blockIdx.y;
    __shared__ float Ash[64][33];
    __shared__ float Bsh[64][33];
    int tid = threadIdx.x, tx = tid & 15, ty = tid >> 4;
    float acc[4][4] = {};
    for (int k0 = 0; k0 < Dn; k0 += 32) {
        int r = tid >> 2, cc = (tid & 3) * 8;
        {
            int bp = mt * 64 + r;
            int bb = bp >> 3, p = bp & 7;
            size_t off = ((size_t)bb * 128 + h * 8 + p) * Dn + k0 + cc;
#pragma unroll
            for (int i = 0; i < 8; i++)
                Ash[r][cc + i] = Up0[off + i] + Up1[off + i] + Up2[off + i];
        }
        {
            const float* src = &in_w[(size_t)(2 * Dn + h * 64 + r) * Dn + k0 + cc];
#pragma unroll
            for (int i = 0; i < 8; i++) Bsh[r][cc + i] = src[i];
        }
        __syncthreads();
#pragma unroll
        for (int kk = 0; kk < 32; kk++) {
            float a[4], bb2[4];
#pragma unroll
            for (int i = 0; i < 4; i++) a[i] = Ash[ty * 4 + i][kk];
#pragma unroll
            for (int j = 0; j < 4; j++) bb2[j] = Bsh[tx * 4 + j][kk];
#pragma unroll
            for (int i = 0; i < 4; i++)
#pragma unroll
                for (int j = 0; j < 4; j++)
                    acc[i][j] = fmaf(a[i], bb2[j], acc[i][j]);
        }
        __syncthreads();
    }
#pragma unroll
    for (int i = 0; i < 4; i++) {
        int bp = mt * 64 + ty * 4 + i;
#pragma unroll
        for (int j = 0; j < 4; j++) {
            int d = tx * 4 + j;
            ctx[(size_t)bp * Dn + h * 64 + d] = acc[i][j] + in_b[2 * Dn + h * 64 + d];
        }
    }
}

// ---------------------------------------------------------------- generic f32 C[M,N] = A[M,K] @ B[N,K]^T + bias (small GEMMs)
__global__ void gemm_abT(const float* __restrict__ A, const float* __restrict__ B,
                         const float* __restrict__ bias, float* __restrict__ C,
                         int M, int N, int K) {
    __shared__ float Ash[64][33];
    __shared__ float Bsh[64][33];
    int m0 = blockIdx.x * 64, n0 = blockIdx.y * 64;
    int tid = threadIdx.x, tx = tid & 15, ty = tid >> 4;
    float acc[4][4] = {};
    for (int k0 = 0; k0 < K; k0 += 32) {
        int r = tid >> 2, cc = (tid & 3) * 8;
        {
            int row = m0 + r;
            int rs = (row < M) ? row : (M - 1);
            bool ok = row < M;
            const float* src = &A[(size_t)rs * K + k0 + cc];
#pragma unroll
            for (int i = 0; i < 8; i++) Ash[r][cc + i] = ok ? src[i] : 0.0f;
        }
        {
            const float* src = &B[(size_t)(n0 + r) * K + k0 + cc];
#pragma unroll
            for (int i = 0; i < 8; i++) Bsh[r][cc + i] = src[i];
        }
        __syncthreads();
#pragma unroll
        for (int kk = 0; kk < 32; kk++) {
            float a[4], bb[4];
#pragma unroll
            for (int i = 0; i < 4; i++) a[i] = Ash[ty * 4 + i][kk];
#pragma unroll
            for (int j = 0; j < 4; j++) bb[j] = Bsh[tx * 4 + j][kk];
#pragma unroll
            for (int i = 0; i < 4; i++)
#pragma unroll
                for (int j = 0; j < 4; j++)
                    acc[i][j] = fmaf(a[i], bb[j], acc[i][j]);
        }
        __syncthreads();
    }
#pragma unroll
    for (int i = 0; i < 4; i++) {
        int row = m0 + ty * 4 + i;
        if (row < M) {
#pragma unroll
            for (int j = 0; j < 4; j++) {
                int col = n0 + tx * 4 + j;
                C[(size_t)row * N + col] = acc[i][j] + bias[col];
            }
        }
    }
}

// ---------------------------------------------------------------- bf16 MFMA GEMM: C[M,1024] = A_bf[M,1024] @ B_bf[1024,1024]^T + bias
__global__ __launch_bounds__(256) void wgemm_mfma(const short* __restrict__ Abf,
                                                  const short* __restrict__ Bbf,
                                                  const float* __restrict__ bias,
                                                  float* __restrict__ C, int M) {
    int wave = threadIdx.x >> 6, lane = threadIdx.x & 63;
    int m0 = blockIdx.x * 64 + (wave >> 1) * 32;
    int n0 = blockIdx.y * 64 + (wave & 1) * 32;
    int koff = (lane >> 4) * 8;
    f32x4 acc[2][2] = {};
    int ra0 = min(m0 + (lane & 15), M - 1);
    int ra1 = min(m0 + 16 + (lane & 15), M - 1);
    const short* a0p = Abf + (size_t)ra0 * Dn + koff;
    const short* a1p = Abf + (size_t)ra1 * Dn + koff;
    const short* b0p = Bbf + (size_t)(n0 + (lane & 15)) * Dn + koff;
    const short* b1p = Bbf + (size_t)(n0 + 16 + (lane & 15)) * Dn + koff;
    for (int k0 = 0; k0 < Dn; k0 += 32) {
        short8 av0 = *(const short8*)(a0p + k0);
        short8 av1 = *(const short8*)(a1p + k0);
        short8 bv0 = *(const short8*)(b0p + k0);
        short8 bv1 = *(const short8*)(b1p + k0);
        acc[0][0] = __builtin_amdgcn_mfma_f32_16x16x32_bf16(av0, bv0, acc[0][0], 0, 0, 0);
        acc[0][1] = __builtin_amdgcn_mfma_f32_16x16x32_bf16(av0, bv1, acc[0][1], 0, 0, 0);
        acc[1][0] = __builtin_amdgcn_mfma_f32_16x16x32_bf16(av1, bv0, acc[1][0], 0, 0, 0);
        acc[1][1] = __builtin_amdgcn_mfma_f32_16x16x32_bf16(av1, bv1, acc[1][1], 0, 0, 0);
    }
#pragma unroll
    for (int mf = 0; mf < 2; mf++) {
        int row0 = m0 + mf * 16 + (lane >> 4) * 4;
#pragma unroll
        for (int nf = 0; nf < 2; nf++) {
            int col = n0 + nf * 16 + (lane & 15);
            float bval = bias[col];
#pragma unroll
            for (int r = 0; r < 4; r++) {
                int row = row0 + r;
                if (row < M) C[(size_t)row * Dn + col] = acc[mf][nf][r] + bval;
            }
        }
    }
}

// ---------------------------------------------------------------- block sum helper
__device__ __forceinline__ float block_sum(float v, float* red) {
    int tid = threadIdx.x;
    red[tid] = v;
    __syncthreads();
    for (int off = 128; off > 0; off >>= 1) {
        if (tid < off) red[tid] += red[tid + off];
        __syncthreads();
    }
    float r = red[0];
    __syncthreads();
    return r;
}

// ---------------------------------------------------------------- build summary row + LN_pma + LN_v / LN_g (bf16 out)
__global__ void summary_ln_kernel(const float* __restrict__ hidden,
                                  const float* __restrict__ queries,
                                  const float* __restrict__ pooled,
                                  const int* __restrict__ rsrc,
                                  const float* __restrict__ gpma, const float* __restrict__ bpma,
                                  const float* __restrict__ gv, const float* __restrict__ bv,
                                  const float* __restrict__ gg, const float* __restrict__ bg,
                                  short* __restrict__ lnv, short* __restrict__ lng) {
    __shared__ float red[256];
    int b = blockIdx.x, t = blockIdx.y, tid = threadIdx.x;
    float x[4];
    if (t == 0) {
#pragma unroll
        for (int i = 0; i < 4; i++)
            x[i] = hidden[(size_t)b * Sn * Dn + tid + i * 256];
    } else if (t < 1 + Pn) {
        int p = t - 1;
#pragma unroll
        for (int i = 0; i < 4; i++) {
            int c = tid + i * 256;
            x[i] = queries[p * Dn + c] + pooled[((size_t)b * Pn + p) * Dn + c];
        }
    } else {
        int src = rsrc[b * RECn + (t - 9)];
        if (src >= 0) {
#pragma unroll
            for (int i = 0; i < 4; i++)
                x[i] = hidden[((size_t)b * Sn + src) * Dn + tid + i * 256];
        } else {
#pragma unroll
            for (int i = 0; i < 4; i++) x[i] = 0.0f;
        }
    }
    if (t >= 1 && t < 1 + Pn) {
        float mu = block_sum(x[0] + x[1] + x[2] + x[3], red) * (1.0f / Dn);
        float d2 = 0.0f;
#pragma unroll
        for (int i = 0; i < 4; i++) { float d = x[i] - mu; d2 += d * d; }
        float inv = rsqrtf(block_sum(d2, red) * (1.0f / Dn) + 1e-5f);
#pragma unroll
        for (int i = 0; i < 4; i++) {
            int c = tid + i * 256;
            x[i] = (x[i] - mu) * inv * gpma[c] + bpma[c];
        }
    }
    float mu = block_sum(x[0] + x[1] + x[2] + x[3], red) * (1.0f / Dn);
    float d2 = 0.0f;
#pragma unroll
    for (int i = 0; i < 4; i++) { float d = x[i] - mu; d2 += d * d; }
    float inv = rsqrtf(block_sum(d2, red) * (1.0f / Dn) + 1e-5f);
    size_t row = (size_t)(b * Tn + t) * Dn;
#pragma unroll
    for (int i = 0; i < 4; i++) {
        int c = tid + i * 256;
        float xh = (x[i] - mu) * inv;
        lnv[row + c] = f2bf(xh * gv[c] + bv[c]);
        lng[row + c] = f2bf(xh * gg[c] + bg[c]);
    }
}

// ---------------------------------------------------------------- gated = sigmoid(c2) * silu(c1) * mask
__global__ void gated_kernel(const float* __restrict__ c1, const float* __restrict__ c2,
                             const float* __restrict__ maskf, float* __restrict__ out) {
    int gi = blockIdx.x * blockDim.x + threadIdx.x;
    int row = gi >> 10;
    float m = maskf[row];
    float a = c1[gi], g = c2[gi];
    float sv = a / (1.0f + expf(-a));
    float sg = 1.0f / (1.0f + expf(-g));
    out[gi] = sg * sv * m;
}

// ================================================================ launch
extern "C" void kernel_launch(void* const* d_in, const int* in_sizes, int n_in,
                              void* d_out, int out_size, void* d_ws, size_t ws_size,
                              hipStream_t stream) {
    const float* hidden = (const float*)d_in[0];
    const void* valid_raw = d_in[1];
    const float* queries = (const float*)d_in[2];
    const float* in_w = (const float*)d_in[3];
    const float* in_b = (const float*)d_in[4];
    const float* out_w = (const float*)d_in[5];
    const float* out_b = (const float*)d_in[6];
    const float* ln_pma_g = (const float*)d_in[7];
    const float* ln_pma_b = (const float*)d_in[8];
    const float* ln_v_g = (const float*)d_in[9];
    const float* ln_v_b = (const float*)d_in[10];
    const float* W_v = (const float*)d_in[11];
    const float* b_v = (const float*)d_in[12];
    const float* ln_g_g = (const float*)d_in[13];
    const float* ln_g_b = (const float*)d_in[14];
    const float* W_g = (const float*)d_in[15];
    const float* b_g = (const float*)d_in[16];

    float* ws = (float*)d_ws;
    float* out = (float*)d_out;

    // workspace layout (float offsets):
    float* SC      = ws;                         // scores f32: 4,194,304 f (dead after softmax)
    short* attn_bf = (short*)(ws + 4194304);     // 2,097,152 f worth
    float* Up0     = ws + 6291456;               // 2,097,152 f
    float* Up1     = ws;                         // overlay in dead SC region
    float* Up2     = ws + 2097152;               // overlay in dead SC region
    float* qbuf    = ws + 8388608;               // 8,192
    short* Amat_bf = (short*)(ws + 8396800);     // 65,536 f
    float* c0      = ws + 8462336;               // 256
    float* ctx     = ws + 8462592;               // 131,072
    float* pooled  = ws + 8593664;               // 131,072
    short* Wv_bf   = (short*)(ws + 8724736);     // 524,288 f
    short* Wg_bf   = (short*)(ws + 9249024);     // 524,288 f
    int*   ivals   = (int*)(ws + 9773312);
    int* totals = ivals;                         // 16
    int* rsrc = ivals + 16;                      // 1024
    int* flag = ivals + 16 + 1024;               // 16
    unsigned char* canon = (unsigned char*)(ivals + 16 + 1024 + 16); // 32768 B
    // post-ctx overlays in SC region (Up1/Up2 dead after ctx):
    short* lnv_bf = (short*)ws;                  // 598,016 f worth
    short* lng_bf = (short*)(ws + 622592);
    float* c1 = ws + 1245184;
    float* c2 = ws + 2441216;                    // ends 3,637,248 < 4,194,304 OK
    float* maskf = out + (size_t)Bn * Tn * Dn;

    const int M2 = Bn * Tn; // 1168

    detect_mask_kernel<<<1, 256, 0, stream>>>((const unsigned char*)valid_raw, flag);
    canon_mask_kernel<<<(Bn * Sn) / 256, 256, 0, stream>>>(valid_raw, flag, canon);
    prep_kernel<<<Bn, 256, 0, stream>>>(canon, totals, rsrc, maskf);
    q_kernel<<<(Pn * Dn) / 4, 256, 0, stream>>>(queries, in_w, in_b, qbuf);
    A_kernel<<<dim3(Hn, 4), 256, 0, stream>>>(qbuf, in_w, in_b, Amat_bf, c0);
    wcvt_kernel<<<512, 256, 0, stream>>>(W_v, Wv_bf, Dn * Dn);
    wcvt_kernel<<<512, 256, 0, stream>>>(W_g, Wg_bf, Dn * Dn);
    scores_mfma<<<(Bn * Sn) / 16, 256, 0, stream>>>(hidden, Amat_bf, c0, canon, SC);
    softmax_kernel<<<Bn * 128, 256, 0, stream>>>(SC, attn_bf);
    U_mfma<<<dim3(16, Bn, 3), 512, 0, stream>>>(attn_bf, hidden, Up0, Up1, Up2);
    ctx_kernel<<<dim3(Hn, 2), 256, 0, stream>>>(Up0, Up1, Up2, in_w, in_b, ctx);
    gemm_abT<<<dim3(2, 16), 256, 0, stream>>>(ctx, out_w, out_b, pooled, Bn * Pn, Dn, Dn);
    summary_ln_kernel<<<dim3(Bn, Tn), 256, 0, stream>>>(hidden, queries, pooled, rsrc,
                                                        ln_pma_g, ln_pma_b, ln_v_g, ln_v_b,
                                                        ln_g_g, ln_g_b, lnv_bf, lng_bf);
    wgemm_mfma<<<dim3((M2 + 63) / 64, 16), 256, 0, stream>>>(lnv_bf, Wv_bf, b_v, c1, M2);
    wgemm_mfma<<<dim3((M2 + 63) / 64, 16), 256, 0, stream>>>(lng_bf, Wg_bf, b_g, c2, M2);
    gated_kernel<<<(Bn * Tn * Dn) / 256, 256, 0, stream>>>(c1, c2, maskf, out);
}

// Round 5
// 380.839 us; speedup vs baseline: 2.1964x; 1.1059x over previous
//
#include <hip/hip_runtime.h>
#include <hip/hip_bf16.h>
#include <math.h>

// Dims fixed by setup_inputs(): B=16, S=2048, D=1024, H=16, hd=64, P=8,
// cls=1, pma=8, recent=64, T=73.

#define Bn 16
#define Sn 2048
#define Dn 1024
#define Hn 16
#define Pn 8
#define Tn 73
#define RECn 64

typedef __attribute__((ext_vector_type(8))) short short8;
typedef __attribute__((ext_vector_type(4))) float f32x4;

__device__ __forceinline__ short f2bf(float x) {
    union { __hip_bfloat16 h; short s; } u;
    u.h = __float2bfloat16(x);   // native v_cvt, RNE
    return u.s;
}

// ---------------------------------------------------------------- mask dtype detect
__global__ void detect_mask_kernel(const unsigned char* __restrict__ raw,
                                   int* __restrict__ flag) {
    __shared__ int any;
    if (threadIdx.x == 0) any = 0;
    __syncthreads();
    const uint4* r4 = (const uint4*)raw;
    int local = 0;
    for (int i = threadIdx.x; i < (Bn * Sn) / 16; i += blockDim.x) {
        uint4 w = r4[i];
        if ((w.x & 0xFFFFFF00u) | (w.y & 0xFFFFFF00u) |
            (w.z & 0xFFFFFF00u) | (w.w & 0xFFFFFF00u)) local = 1;
    }
    if (local) any = 1; // benign race
    __syncthreads();
    if (threadIdx.x == 0) *flag = any;
}

__global__ void canon_mask_kernel(const void* __restrict__ raw,
                                  const int* __restrict__ flag,
                                  unsigned char* __restrict__ canon) {
    int i = blockIdx.x * blockDim.x + threadIdx.x;
    if (i >= Bn * Sn) return;
    unsigned char v;
    if (*flag)
        v = ((const unsigned char*)raw)[i] ? 1 : 0;
    else
        v = ((const int*)raw)[i] ? 1 : 0;
    canon[i] = v;
}

// ---------------------------------------------------------------- prep
__global__ void prep_kernel(const unsigned char* __restrict__ valid,
                            int* __restrict__ totals, int* __restrict__ rsrc,
                            float* __restrict__ maskf) {
    int b = blockIdx.x, t = threadIdx.x;
    const int SP = Sn - 1; // 2047
    __shared__ int lc[256];
    if (t < RECn) rsrc[b * RECn + t] = -1;

    int base = t * 8;
    unsigned char m[8];
    int cnt = 0;
#pragma unroll
    for (int i = 0; i < 8; i++) {
        int idx = base + i;
        m[i] = (idx < SP) ? valid[(size_t)b * Sn + 1 + idx] : (unsigned char)0;
        cnt += m[i] ? 1 : 0;
    }
    lc[t] = cnt;
    __syncthreads();
    for (int off = 1; off < 256; off <<= 1) {
        int add = (t >= off) ? lc[t - off] : 0;
        __syncthreads();
        lc[t] += add;
        __syncthreads();
    }
    int total = lc[255];
    int run = lc[t] - cnt; // exclusive prefix
#pragma unroll
    for (int i = 0; i < 8; i++) {
        if (m[i]) {
            run++;
            int rank = total - run;
            if (rank < RECn) rsrc[b * RECn + (RECn - 1 - rank)] = base + i + 1;
        }
    }
    if (t == 0) totals[b] = total;
    if (t < Tn) {
        float mv;
        if (t == 0) mv = valid[(size_t)b * Sn] ? 1.0f : 0.0f;
        else if (t < 1 + Pn) mv = 1.0f;
        else mv = ((t - 9) >= RECn - total) ? 1.0f : 0.0f;
        maskf[b * Tn + t] = mv;
    }
}

// ---------------------------------------------------------------- q = queries @ Wq^T + bq
__global__ void q_kernel(const float* __restrict__ queries,
                         const float* __restrict__ in_w,
                         const float* __restrict__ in_b,
                         float* __restrict__ q) {
    int wid = (blockIdx.x * blockDim.x + threadIdx.x) >> 6;
    int lane = threadIdx.x & 63;
    if (wid >= Pn * Dn) return;
    int p = wid >> 10, j = wid & 1023;
    float acc = 0.0f;
    for (int c = lane; c < Dn; c += 64)
        acc += queries[p * Dn + c] * in_w[(size_t)j * Dn + c];
#pragma unroll
    for (int off = 32; off > 0; off >>= 1) acc += __shfl_down(acc, off);
    if (lane == 0) q[wid] = acc + in_b[j];
}

// ---------------------------------------------------------------- A_bf[h*8+p,c] = bf16((q_h[p] . Wk_h[:,c]) / 8) ; c0
__global__ void A_kernel(const float* __restrict__ q,
                         const float* __restrict__ in_w,
                         const float* __restrict__ in_b,
                         short* __restrict__ Amat_bf, float* __restrict__ c0) {
    int h = blockIdx.x, cblk = blockIdx.y;
    int c = cblk * 256 + threadIdx.x;
    __shared__ float qs[8][64];
    for (int i = threadIdx.x; i < 512; i += 256) {
        int p = i >> 6, d = i & 63;
        qs[p][d] = q[p * Dn + h * 64 + d];
    }
    __syncthreads();
    float acc[8] = {};
#pragma unroll 8
    for (int d = 0; d < 64; d++) {
        float w = in_w[(size_t)(Dn + h * 64 + d) * Dn + c];
#pragma unroll
        for (int p = 0; p < 8; p++) acc[p] = fmaf(qs[p][d], w, acc[p]);
    }
#pragma unroll
    for (int p = 0; p < 8; p++)
        Amat_bf[(size_t)(h * 8 + p) * Dn + c] = f2bf(acc[p] * 0.125f);
    if (cblk == 0 && threadIdx.x < 8) {
        int p = threadIdx.x;
        float a = 0.0f;
        for (int d = 0; d < 64; d++) a += qs[p][d] * in_b[Dn + h * 64 + d];
        c0[h * 8 + p] = a * 0.125f;
    }
}

// ---------------------------------------------------------------- f32 -> bf16 elementwise (weights)
__global__ void wcvt_kernel(const float* __restrict__ w, short* __restrict__ wbf, int n) {
    int i = (blockIdx.x * blockDim.x + threadIdx.x) * 8;
    if (i >= n) return;
    f32x4 x0 = *(const f32x4*)(w + i);
    f32x4 x1 = *(const f32x4*)(w + i + 4);
    short8 o;
#pragma unroll
    for (int j = 0; j < 4; j++) { o[j] = f2bf(x0[j]); o[j + 4] = f2bf(x1[j]); }
    *(short8*)(wbf + i) = o;
}

// ---------------------------------------------------------------- scores[b,hp,s] = hidden[b,s,:]@A[hp,:] + c0 (MFMA bf16), masked
// 2048 blocks x 64 threads (1 wave): wave owns 16 s-rows x all 128 hp.
// 8 independent acc chains + next-iter hidden prefetch for latency hiding.
__global__ __launch_bounds__(64) void scores_mfma(const float* __restrict__ hidden,
                                                  const short* __restrict__ Amat_bf,
                                                  const float* __restrict__ c0,
                                                  const unsigned char* __restrict__ valid,
                                                  float* __restrict__ scores) {
    int lane = threadIdx.x & 63;
    int l15 = lane & 15;
    int m0 = blockIdx.x * 16;                  // row in [0, 32768)
    int b = m0 >> 11, s_base = m0 & 2047;
    int koff = (lane >> 4) * 8;
    const float* aptr = hidden + (size_t)(m0 + l15) * Dn + koff;
    const short* bbase = Amat_bf + (size_t)l15 * Dn + koff;
    f32x4 acc[8] = {};
    f32x4 ca0 = *(const f32x4*)(aptr);
    f32x4 ca1 = *(const f32x4*)(aptr + 4);
#pragma unroll 4
    for (int k0 = 0; k0 < Dn - 32; k0 += 32) {
        f32x4 na0 = *(const f32x4*)(aptr + k0 + 32);
        f32x4 na1 = *(const f32x4*)(aptr + k0 + 36);
        short8 av;
#pragma unroll
        for (int i = 0; i < 4; i++) { av[i] = f2bf(ca0[i]); av[i + 4] = f2bf(ca1[i]); }
#pragma unroll
        for (int nt = 0; nt < 8; nt++) {
            short8 bv = *(const short8*)(bbase + (size_t)nt * 16 * Dn + k0);
            acc[nt] = __builtin_amdgcn_mfma_f32_16x16x32_bf16(av, bv, acc[nt], 0, 0, 0);
        }
        ca0 = na0; ca1 = na1;
    }
    {   // last K-step (k0 = Dn-32)
        short8 av;
#pragma unroll
        for (int i = 0; i < 4; i++) { av[i] = f2bf(ca0[i]); av[i + 4] = f2bf(ca1[i]); }
#pragma unroll
        for (int nt = 0; nt < 8; nt++) {
            short8 bv = *(const short8*)(bbase + (size_t)nt * 16 * Dn + (Dn - 32));
            acc[nt] = __builtin_amdgcn_mfma_f32_16x16x32_bf16(av, bv, acc[nt], 0, 0, 0);
        }
    }
    // epilogue: C/D layout col=lane&15 (hp within tile), row=(lane>>4)*4+reg (s)
    int srow = s_base + (lane >> 4) * 4;
    const unsigned char* vptr = valid + (size_t)b * Sn + srow;
    bool ok0 = vptr[0] != 0, ok1 = vptr[1] != 0, ok2 = vptr[2] != 0, ok3 = vptr[3] != 0;
#pragma unroll
    for (int nt = 0; nt < 8; nt++) {
        int hp = nt * 16 + l15;
        float cc = c0[hp];
        f32x4 st;
        st[0] = ok0 ? acc[nt][0] + cc : -1.0e9f;
        st[1] = ok1 ? acc[nt][1] + cc : -1.0e9f;
        st[2] = ok2 ? acc[nt][2] + cc : -1.0e9f;
        st[3] = ok3 ? acc[nt][3] + cc : -1.0e9f;
        *(f32x4*)(scores + (size_t)(b * 128 + hp) * Sn + srow) = st;
    }
}

// ---------------------------------------------------------------- softmax over s; writes bf16 attn
__global__ __launch_bounds__(256) void softmax_kernel(const float* __restrict__ scores,
                                                      short* __restrict__ attn_bf) {
    const float* row = scores + (size_t)blockIdx.x * Sn;
    short* orow = attn_bf + (size_t)blockIdx.x * Sn;
    int t = threadIdx.x;
    __shared__ float red[256];
    f32x4 v0 = *(const f32x4*)(row + t * 8);
    f32x4 v1 = *(const f32x4*)(row + t * 8 + 4);
    float mx = -1.0e30f;
#pragma unroll
    for (int i = 0; i < 4; i++) { mx = fmaxf(mx, v0[i]); mx = fmaxf(mx, v1[i]); }
    red[t] = mx;
    __syncthreads();
    for (int off = 128; off > 0; off >>= 1) {
        if (t < off) red[t] = fmaxf(red[t], red[t + off]);
        __syncthreads();
    }
    mx = red[0];
    __syncthreads();
    float e[8];
    float sum = 0.0f;
#pragma unroll
    for (int i = 0; i < 4; i++) {
        e[i] = expf(v0[i] - mx); sum += e[i];
        e[i + 4] = expf(v1[i] - mx); sum += e[i + 4];
    }
    red[t] = sum;
    __syncthreads();
    for (int off = 128; off > 0; off >>= 1) {
        if (t < off) red[t] += red[t + off];
        __syncthreads();
    }
    float inv = 1.0f / red[0];
    short8 o;
#pragma unroll
    for (int i = 0; i < 8; i++) o[i] = f2bf(e[i] * inv);
    *(short8*)(orow + t * 8) = o;
}

// ---------------------------------------------------------------- U partials: Up[b,hp,c] = sum_{s in z-chunk} attn[b,hp,s]*hidden[b,s,c]
// grid (16 n-tiles, 16 b, 3 z) x 512 threads (8 waves). Tile 128(hp) x 64(c).
// Double-buffered LDS transpose staging: 1 barrier per 32-K chunk; global
// loads (hidden chunk + attn frag) prefetched one chunk ahead.
__global__ __launch_bounds__(512) void U_mfma(const short* __restrict__ attn_bf,
                                              const float* __restrict__ hidden,
                                              float* __restrict__ Up0,
                                              float* __restrict__ Up1,
                                              float* __restrict__ Up2) {
    int b = blockIdx.y, n0 = blockIdx.x * 64, z = blockIdx.z;
    int zbase = z * 704;
    int zlen = (z == 2) ? 640 : 704;
    float* Up = (z == 0) ? Up0 : (z == 1) ? Up1 : Up2;

    int tid = threadIdx.x, wave = tid >> 6, lane = tid & 63;
    int l15 = lane & 15;
    __shared__ short ldsB[2][64][40];
    int kr = tid & 31, nc = ((tid >> 5) & 15) * 4; // staging: (k=kr, c=nc..nc+3)
    int koff = (lane >> 4) * 8;
    f32x4 acc[4] = {};
    const short* aBase = attn_bf + ((size_t)b * 128 + wave * 16 + l15) * Sn + zbase + koff;
    const float* hBase = hidden + ((size_t)b * Sn + zbase + kr) * Dn + n0 + nc;

    int nk = zlen >> 5;                       // 22 or 20 chunks
    f32x4 h = *(const f32x4*)(hBase);
#pragma unroll
    for (int i = 0; i < 4; i++) ldsB[0][nc + i][kr] = f2bf(h[i]);
    short8 av = *(const short8*)(aBase);

    for (int ic = 0; ic < nk; ic++) {
        int cur = ic & 1;
        bool more = (ic + 1 < nk);
        f32x4 hn;
        short8 avn;
        if (more) {
            hn = *(const f32x4*)(hBase + (size_t)(ic + 1) * 32 * Dn);
            avn = *(const short8*)(aBase + (ic + 1) * 32);
        }
        __syncthreads();                      // buf[cur] writes visible
#pragma unroll
        for (int nf = 0; nf < 4; nf++) {
            short8 bv = *(const short8*)(&ldsB[cur][nf * 16 + l15][koff]);
            acc[nf] = __builtin_amdgcn_mfma_f32_16x16x32_bf16(av, bv, acc[nf], 0, 0, 0);
        }
        if (more) {
#pragma unroll
            for (int i = 0; i < 4; i++) ldsB[cur ^ 1][nc + i][kr] = f2bf(hn[i]);
            av = avn;
        }
    }
    int hp = wave * 16 + (lane >> 4) * 4;
#pragma unroll
    for (int nf = 0; nf < 4; nf++) {
        int c = n0 + nf * 16 + l15;
        float* up = Up + (size_t)(b * 128 + hp) * Dn + c;
#pragma unroll
        for (int r = 0; r < 4; r++) up[(size_t)r * Dn] = acc[nf][r];
    }
}

// ---------------------------------------------------------------- ctx[bp, h*64+d] = (Up0+Up1+Up2)[b,h*8+p,:] . Wv[h*64+d,:] + bv
__global__ void ctx_kernel(const float* __restrict__ Up0,
                           const float* __restrict__ Up1,
                           const float* __restrict__ Up2,
                           const float* __restrict__ in_w,
                           const float* __restrict__ in_b,
                           float* __restrict__ ctx) {
    int h = blockIdx.x, mt = blockIdx.y;
    __shared__ float Ash[64][33];
    __shared__ float Bsh[64][33];
    int tid = threadIdx.x, tx = tid & 15, ty = tid >> 4;
    float acc[4][4] = {};
    for (int k0 = 0; k0 < Dn; k0 += 32) {
        int r = tid >> 2, cc = (tid & 3) * 8;
        {
            int bp = mt * 64 + r;
            int bb = bp >> 3, p = bp & 7;
            size_t off = ((size_t)bb * 128 + h * 8 + p) * Dn + k0 + cc;
#pragma unroll
            for (int i = 0; i < 8; i++)
                Ash[r][cc + i] = Up0[off + i] + Up1[off + i] + Up2[off + i];
        }
        {
            const float* src = &in_w[(size_t)(2 * Dn + h * 64 + r) * Dn + k0 + cc];
#pragma unroll
            for (int i = 0; i < 8; i++) Bsh[r][cc + i] = src[i];
        }
        __syncthreads();
#pragma unroll
        for (int kk = 0; kk < 32; kk++) {
            float a[4], bb2[4];
#pragma unroll
            for (int i = 0; i < 4; i++) a[i] = Ash[ty * 4 + i][kk];
#pragma unroll
            for (int j = 0; j < 4; j++) bb2[j] = Bsh[tx * 4 + j][kk];
#pragma unroll
            for (int i = 0; i < 4; i++)
#pragma unroll
                for (int j = 0; j < 4; j++)
                    acc[i][j] = fmaf(a[i], bb2[j], acc[i][j]);
        }
        __syncthreads();
    }
#pragma unroll
    for (int i = 0; i < 4; i++) {
        int bp = mt * 64 + ty * 4 + i;
#pragma unroll
        for (int j = 0; j < 4; j++) {
            int d = tx * 4 + j;
            ctx[(size_t)bp * Dn + h * 64 + d] = acc[i][j] + in_b[2 * Dn + h * 64 + d];
        }
    }
}

// ---------------------------------------------------------------- generic f32 C[M,N] = A[M,K] @ B[N,K]^T + bias (small GEMMs)
__global__ void gemm_abT(const float* __restrict__ A, const float* __restrict__ B,
                         const float* __restrict__ bias, float* __restrict__ C,
                         int M, int N, int K) {
    __shared__ float Ash[64][33];
    __shared__ float Bsh[64][33];
    int m0 = blockIdx.x * 64, n0 = blockIdx.y * 64;
    int tid = threadIdx.x, tx = tid & 15, ty = tid >> 4;
    float acc[4][4] = {};
    for (int k0 = 0; k0 < K; k0 += 32) {
        int r = tid >> 2, cc = (tid & 3) * 8;
        {
            int row = m0 + r;
            int rs = (row < M) ? row : (M - 1);
            bool ok = row < M;
            const float* src = &A[(size_t)rs * K + k0 + cc];
#pragma unroll
            for (int i = 0; i < 8; i++) Ash[r][cc + i] = ok ? src[i] : 0.0f;
        }
        {
            const float* src = &B[(size_t)(n0 + r) * K + k0 + cc];
#pragma unroll
            for (int i = 0; i < 8; i++) Bsh[r][cc + i] = src[i];
        }
        __syncthreads();
#pragma unroll
        for (int kk = 0; kk < 32; kk++) {
            float a[4], bb[4];
#pragma unroll
            for (int i = 0; i < 4; i++) a[i] = Ash[ty * 4 + i][kk];
#pragma unroll
            for (int j = 0; j < 4; j++) bb[j] = Bsh[tx * 4 + j][kk];
#pragma unroll
            for (int i = 0; i < 4; i++)
#pragma unroll
                for (int j = 0; j < 4; j++)
                    acc[i][j] = fmaf(a[i], bb[j], acc[i][j]);
        }
        __syncthreads();
    }
#pragma unroll
    for (int i = 0; i < 4; i++) {
        int row = m0 + ty * 4 + i;
        if (row < M) {
#pragma unroll
            for (int j = 0; j < 4; j++) {
                int col = n0 + tx * 4 + j;
                C[(size_t)row * N + col] = acc[i][j] + bias[col];
            }
        }
    }
}

// ---------------------------------------------------------------- bf16 MFMA GEMM: C[M,1024] = A_bf[M,1024] @ B_bf[1024,1024]^T + bias
__global__ __launch_bounds__(256) void wgemm_mfma(const short* __restrict__ Abf,
                                                  const short* __restrict__ Bbf,
                                                  const float* __restrict__ bias,
                                                  float* __restrict__ C, int M) {
    int wave = threadIdx.x >> 6, lane = threadIdx.x & 63;
    int m0 = blockIdx.x * 64 + (wave >> 1) * 32;
    int n0 = blockIdx.y * 64 + (wave & 1) * 32;
    int koff = (lane >> 4) * 8;
    f32x4 acc[2][2] = {};
    int ra0 = min(m0 + (lane & 15), M - 1);
    int ra1 = min(m0 + 16 + (lane & 15), M - 1);
    const short* a0p = Abf + (size_t)ra0 * Dn + koff;
    const short* a1p = Abf + (size_t)ra1 * Dn + koff;
    const short* b0p = Bbf + (size_t)(n0 + (lane & 15)) * Dn + koff;
    const short* b1p = Bbf + (size_t)(n0 + 16 + (lane & 15)) * Dn + koff;
    for (int k0 = 0; k0 < Dn; k0 += 32) {
        short8 av0 = *(const short8*)(a0p + k0);
        short8 av1 = *(const short8*)(a1p + k0);
        short8 bv0 = *(const short8*)(b0p + k0);
        short8 bv1 = *(const short8*)(b1p + k0);
        acc[0][0] = __builtin_amdgcn_mfma_f32_16x16x32_bf16(av0, bv0, acc[0][0], 0, 0, 0);
        acc[0][1] = __builtin_amdgcn_mfma_f32_16x16x32_bf16(av0, bv1, acc[0][1], 0, 0, 0);
        acc[1][0] = __builtin_amdgcn_mfma_f32_16x16x32_bf16(av1, bv0, acc[1][0], 0, 0, 0);
        acc[1][1] = __builtin_amdgcn_mfma_f32_16x16x32_bf16(av1, bv1, acc[1][1], 0, 0, 0);
    }
#pragma unroll
    for (int mf = 0; mf < 2; mf++) {
        int row0 = m0 + mf * 16 + (lane >> 4) * 4;
#pragma unroll
        for (int nf = 0; nf < 2; nf++) {
            int col = n0 + nf * 16 + (lane & 15);
            float bval = bias[col];
#pragma unroll
            for (int r = 0; r < 4; r++) {
                int row = row0 + r;
                if (row < M) C[(size_t)row * Dn + col] = acc[mf][nf][r] + bval;
            }
        }
    }
}

// ---------------------------------------------------------------- block sum helper
__device__ __forceinline__ float block_sum(float v, float* red) {
    int tid = threadIdx.x;
    red[tid] = v;
    __syncthreads();
    for (int off = 128; off > 0; off >>= 1) {
        if (tid < off) red[tid] += red[tid + off];
        __syncthreads();
    }
    float r = red[0];
    __syncthreads();
    return r;
}

// ---------------------------------------------------------------- build summary row + LN_pma + LN_v / LN_g (bf16 out)
__global__ void summary_ln_kernel(const float* __restrict__ hidden,
                                  const float* __restrict__ queries,
                                  const float* __restrict__ pooled,
                                  const int* __restrict__ rsrc,
                                  const float* __restrict__ gpma, const float* __restrict__ bpma,
                                  const float* __restrict__ gv, const float* __restrict__ bv,
                                  const float* __restrict__ gg, const float* __restrict__ bg,
                                  short* __restrict__ lnv, short* __restrict__ lng) {
    __shared__ float red[256];
    int b = blockIdx.x, t = blockIdx.y, tid = threadIdx.x;
    float x[4];
    if (t == 0) {
#pragma unroll
        for (int i = 0; i < 4; i++)
            x[i] = hidden[(size_t)b * Sn * Dn + tid + i * 256];
    } else if (t < 1 + Pn) {
        int p = t - 1;
#pragma unroll
        for (int i = 0; i < 4; i++) {
            int c = tid + i * 256;
            x[i] = queries[p * Dn + c] + pooled[((size_t)b * Pn + p) * Dn + c];
        }
    } else {
        int src = rsrc[b * RECn + (t - 9)];
        if (src >= 0) {
#pragma unroll
            for (int i = 0; i < 4; i++)
                x[i] = hidden[((size_t)b * Sn + src) * Dn + tid + i * 256];
        } else {
#pragma unroll
            for (int i = 0; i < 4; i++) x[i] = 0.0f;
        }
    }
    if (t >= 1 && t < 1 + Pn) {
        float mu = block_sum(x[0] + x[1] + x[2] + x[3], red) * (1.0f / Dn);
        float d2 = 0.0f;
#pragma unroll
        for (int i = 0; i < 4; i++) { float d = x[i] - mu; d2 += d * d; }
        float inv = rsqrtf(block_sum(d2, red) * (1.0f / Dn) + 1e-5f);
#pragma unroll
        for (int i = 0; i < 4; i++) {
            int c = tid + i * 256;
            x[i] = (x[i] - mu) * inv * gpma[c] + bpma[c];
        }
    }
    float mu = block_sum(x[0] + x[1] + x[2] + x[3], red) * (1.0f / Dn);
    float d2 = 0.0f;
#pragma unroll
    for (int i = 0; i < 4; i++) { float d = x[i] - mu; d2 += d * d; }
    float inv = rsqrtf(block_sum(d2, red) * (1.0f / Dn) + 1e-5f);
    size_t row = (size_t)(b * Tn + t) * Dn;
#pragma unroll
    for (int i = 0; i < 4; i++) {
        int c = tid + i * 256;
        float xh = (x[i] - mu) * inv;
        lnv[row + c] = f2bf(xh * gv[c] + bv[c]);
        lng[row + c] = f2bf(xh * gg[c] + bg[c]);
    }
}

// ---------------------------------------------------------------- gated = sigmoid(c2) * silu(c1) * mask
__global__ void gated_kernel(const float* __restrict__ c1, const float* __restrict__ c2,
                             const float* __restrict__ maskf, float* __restrict__ out) {
    int gi = blockIdx.x * blockDim.x + threadIdx.x;
    int row = gi >> 10;
    float m = maskf[row];
    float a = c1[gi], g = c2[gi];
    float sv = a / (1.0f + expf(-a));
    float sg = 1.0f / (1.0f + expf(-g));
    out[gi] = sg * sv * m;
}

// ================================================================ launch
extern "C" void kernel_launch(void* const* d_in, const int* in_sizes, int n_in,
                              void* d_out, int out_size, void* d_ws, size_t ws_size,
                              hipStream_t stream) {
    const float* hidden = (const float*)d_in[0];
    const void* valid_raw = d_in[1];
    const float* queries = (const float*)d_in[2];
    const float* in_w = (const float*)d_in[3];
    const float* in_b = (const float*)d_in[4];
    const float* out_w = (const float*)d_in[5];
    const float* out_b = (const float*)d_in[6];
    const float* ln_pma_g = (const float*)d_in[7];
    const float* ln_pma_b = (const float*)d_in[8];
    const float* ln_v_g = (const float*)d_in[9];
    const float* ln_v_b = (const float*)d_in[10];
    const float* W_v = (const float*)d_in[11];
    const float* b_v = (const float*)d_in[12];
    const float* ln_g_g = (const float*)d_in[13];
    const float* ln_g_b = (const float*)d_in[14];
    const float* W_g = (const float*)d_in[15];
    const float* b_g = (const float*)d_in[16];

    float* ws = (float*)d_ws;
    float* out = (float*)d_out;

    // workspace layout (float offsets):
    float* SC      = ws;                         // scores f32: 4,194,304 f (dead after softmax)
    short* attn_bf = (short*)(ws + 4194304);     // 2,097,152 f worth
    float* Up0     = ws + 6291456;               // 2,097,152 f
    float* Up1     = ws;                         // overlay in dead SC region
    float* Up2     = ws + 2097152;               // overlay in dead SC region
    float* qbuf    = ws + 8388608;               // 8,192
    short* Amat_bf = (short*)(ws + 8396800);     // 65,536 f
    float* c0      = ws + 8462336;               // 256
    float* ctx     = ws + 8462592;               // 131,072
    float* pooled  = ws + 8593664;               // 131,072
    short* Wv_bf   = (short*)(ws + 8724736);     // 524,288 f
    short* Wg_bf   = (short*)(ws + 9249024);     // 524,288 f
    int*   ivals   = (int*)(ws + 9773312);
    int* totals = ivals;                         // 16
    int* rsrc = ivals + 16;                      // 1024
    int* flag = ivals + 16 + 1024;               // 16
    unsigned char* canon = (unsigned char*)(ivals + 16 + 1024 + 16); // 32768 B
    // post-ctx overlays in SC region (Up1/Up2 dead after ctx):
    short* lnv_bf = (short*)ws;                  // 598,016 f worth
    short* lng_bf = (short*)(ws + 622592);
    float* c1 = ws + 1245184;
    float* c2 = ws + 2441216;                    // ends 3,637,248 < 4,194,304 OK
    float* maskf = out + (size_t)Bn * Tn * Dn;

    const int M2 = Bn * Tn; // 1168

    detect_mask_kernel<<<1, 256, 0, stream>>>((const unsigned char*)valid_raw, flag);
    canon_mask_kernel<<<(Bn * Sn) / 256, 256, 0, stream>>>(valid_raw, flag, canon);
    prep_kernel<<<Bn, 256, 0, stream>>>(canon, totals, rsrc, maskf);
    q_kernel<<<(Pn * Dn) / 4, 256, 0, stream>>>(queries, in_w, in_b, qbuf);
    A_kernel<<<dim3(Hn, 4), 256, 0, stream>>>(qbuf, in_w, in_b, Amat_bf, c0);
    wcvt_kernel<<<512, 256, 0, stream>>>(W_v, Wv_bf, Dn * Dn);
    wcvt_kernel<<<512, 256, 0, stream>>>(W_g, Wg_bf, Dn * Dn);
    scores_mfma<<<(Bn * Sn) / 16, 64, 0, stream>>>(hidden, Amat_bf, c0, canon, SC);
    softmax_kernel<<<Bn * 128, 256, 0, stream>>>(SC, attn_bf);
    U_mfma<<<dim3(16, Bn, 3), 512, 0, stream>>>(attn_bf, hidden, Up0, Up1, Up2);
    ctx_kernel<<<dim3(Hn, 2), 256, 0, stream>>>(Up0, Up1, Up2, in_w, in_b, ctx);
    gemm_abT<<<dim3(2, 16), 256, 0, stream>>>(ctx, out_w, out_b, pooled, Bn * Pn, Dn, Dn);
    summary_ln_kernel<<<dim3(Bn, Tn), 256, 0, stream>>>(hidden, queries, pooled, rsrc,
                                                        ln_pma_g, ln_pma_b, ln_v_g, ln_v_b,
                                                        ln_g_g, ln_g_b, lnv_bf, lng_bf);
    wgemm_mfma<<<dim3((M2 + 63) / 64, 16), 256, 0, stream>>>(lnv_bf, Wv_bf, b_v, c1, M2);
    wgemm_mfma<<<dim3((M2 + 63) / 64, 16), 256, 0, stream>>>(lng_bf, Wg_bf, b_g, c2, M2);
    gated_kernel<<<(Bn * Tn * Dn) / 256, 256, 0, stream>>>(c1, c2, maskf, out);
}

// Round 6
// 239.260 us; speedup vs baseline: 3.4961x; 1.5917x over previous
//
#include <hip/hip_runtime.h>
#include <hip/hip_bf16.h>
#include <math.h>

// Dims fixed by setup_inputs(): B=16, S=2048, D=1024, H=16, hd=64, P=8,
// cls=1, pma=8, recent=64, T=73.

#define Bn 16
#define Sn 2048
#define Dn 1024
#define Hn 16
#define Pn 8
#define Tn 73
#define RECn 64

typedef __attribute__((ext_vector_type(8))) short short8;
typedef __attribute__((ext_vector_type(4))) float f32x4;

__device__ __forceinline__ short f2bf(float x) {
    union { __hip_bfloat16 h; short s; } u;
    u.h = __float2bfloat16(x);   // native v_cvt, RNE
    return u.s;
}

// ---------------------------------------------------------------- mask dtype detect
__global__ void detect_mask_kernel(const unsigned char* __restrict__ raw,
                                   int* __restrict__ flag) {
    __shared__ int any;
    if (threadIdx.x == 0) any = 0;
    __syncthreads();
    const uint4* r4 = (const uint4*)raw;
    int local = 0;
    for (int i = threadIdx.x; i < (Bn * Sn) / 16; i += blockDim.x) {
        uint4 w = r4[i];
        if ((w.x & 0xFFFFFF00u) | (w.y & 0xFFFFFF00u) |
            (w.z & 0xFFFFFF00u) | (w.w & 0xFFFFFF00u)) local = 1;
    }
    if (local) any = 1; // benign race
    __syncthreads();
    if (threadIdx.x == 0) *flag = any;
}

__global__ void canon_mask_kernel(const void* __restrict__ raw,
                                  const int* __restrict__ flag,
                                  unsigned char* __restrict__ canon) {
    int i = blockIdx.x * blockDim.x + threadIdx.x;
    if (i >= Bn * Sn) return;
    unsigned char v;
    if (*flag)
        v = ((const unsigned char*)raw)[i] ? 1 : 0;
    else
        v = ((const int*)raw)[i] ? 1 : 0;
    canon[i] = v;
}

// ---------------------------------------------------------------- prep
__global__ void prep_kernel(const unsigned char* __restrict__ valid,
                            int* __restrict__ totals, int* __restrict__ rsrc,
                            float* __restrict__ maskf) {
    int b = blockIdx.x, t = threadIdx.x;
    const int SP = Sn - 1; // 2047
    __shared__ int lc[256];
    if (t < RECn) rsrc[b * RECn + t] = -1;

    int base = t * 8;
    unsigned char m[8];
    int cnt = 0;
#pragma unroll
    for (int i = 0; i < 8; i++) {
        int idx = base + i;
        m[i] = (idx < SP) ? valid[(size_t)b * Sn + 1 + idx] : (unsigned char)0;
        cnt += m[i] ? 1 : 0;
    }
    lc[t] = cnt;
    __syncthreads();
    for (int off = 1; off < 256; off <<= 1) {
        int add = (t >= off) ? lc[t - off] : 0;
        __syncthreads();
        lc[t] += add;
        __syncthreads();
    }
    int total = lc[255];
    int run = lc[t] - cnt; // exclusive prefix
#pragma unroll
    for (int i = 0; i < 8; i++) {
        if (m[i]) {
            run++;
            int rank = total - run;
            if (rank < RECn) rsrc[b * RECn + (RECn - 1 - rank)] = base + i + 1;
        }
    }
    if (t == 0) totals[b] = total;
    if (t < Tn) {
        float mv;
        if (t == 0) mv = valid[(size_t)b * Sn] ? 1.0f : 0.0f;
        else if (t < 1 + Pn) mv = 1.0f;
        else mv = ((t - 9) >= RECn - total) ? 1.0f : 0.0f;
        maskf[b * Tn + t] = mv;
    }
}

// ---------------------------------------------------------------- q = queries @ Wq^T + bq
__global__ void q_kernel(const float* __restrict__ queries,
                         const float* __restrict__ in_w,
                         const float* __restrict__ in_b,
                         float* __restrict__ q) {
    int wid = (blockIdx.x * blockDim.x + threadIdx.x) >> 6;
    int lane = threadIdx.x & 63;
    if (wid >= Pn * Dn) return;
    int p = wid >> 10, j = wid & 1023;
    float acc = 0.0f;
    for (int c = lane; c < Dn; c += 64)
        acc += queries[p * Dn + c] * in_w[(size_t)j * Dn + c];
#pragma unroll
    for (int off = 32; off > 0; off >>= 1) acc += __shfl_down(acc, off);
    if (lane == 0) q[wid] = acc + in_b[j];
}

// ---------------------------------------------------------------- A_bf[h*8+p,c] = bf16((q_h[p] . Wk_h[:,c]) / 8) ; c0
__global__ void A_kernel(const float* __restrict__ q,
                         const float* __restrict__ in_w,
                         const float* __restrict__ in_b,
                         short* __restrict__ Amat_bf, float* __restrict__ c0) {
    int h = blockIdx.x, cblk = blockIdx.y;
    int c = cblk * 256 + threadIdx.x;
    __shared__ float qs[8][64];
    for (int i = threadIdx.x; i < 512; i += 256) {
        int p = i >> 6, d = i & 63;
        qs[p][d] = q[p * Dn + h * 64 + d];
    }
    __syncthreads();
    float acc[8] = {};
#pragma unroll 8
    for (int d = 0; d < 64; d++) {
        float w = in_w[(size_t)(Dn + h * 64 + d) * Dn + c];
#pragma unroll
        for (int p = 0; p < 8; p++) acc[p] = fmaf(qs[p][d], w, acc[p]);
    }
#pragma unroll
    for (int p = 0; p < 8; p++)
        Amat_bf[(size_t)(h * 8 + p) * Dn + c] = f2bf(acc[p] * 0.125f);
    if (cblk == 0 && threadIdx.x < 8) {
        int p = threadIdx.x;
        float a = 0.0f;
        for (int d = 0; d < 64; d++) a += qs[p][d] * in_b[Dn + h * 64 + d];
        c0[h * 8 + p] = a * 0.125f;
    }
}

// ---------------------------------------------------------------- f32 -> bf16 elementwise (weights)
__global__ void wcvt_kernel(const float* __restrict__ w, short* __restrict__ wbf, int n) {
    int i = (blockIdx.x * blockDim.x + threadIdx.x) * 8;
    if (i >= n) return;
    f32x4 x0 = *(const f32x4*)(w + i);
    f32x4 x1 = *(const f32x4*)(w + i + 4);
    short8 o;
#pragma unroll
    for (int j = 0; j < 4; j++) { o[j] = f2bf(x0[j]); o[j + 4] = f2bf(x1[j]); }
    *(short8*)(wbf + i) = o;
}

// ---------------------------------------------------------------- scores[b,hp,s] = hidden[b,s,:]@A[hp,:] + c0 (MFMA bf16), masked
// 512 blocks x 256 threads (4 waves). Block owns 64 s-rows (wave w: 16 rows),
// all 128 hp. Amat K-chunks staged in double-buffered LDS (B-frags via
// ds_read_b128, ~12cyc, instead of per-iter L2 round trips). Hidden
// prefetched 2 chunks ahead in regs.
__global__ __launch_bounds__(256) void scores_mfma(const float* __restrict__ hidden,
                                                   const short* __restrict__ Amat_bf,
                                                   const float* __restrict__ c0,
                                                   const unsigned char* __restrict__ valid,
                                                   float* __restrict__ scores) {
    int tid = threadIdx.x, wave = tid >> 6, lane = tid & 63;
    int l15 = lane & 15, koff = (lane >> 4) * 8;
    int mrow0 = blockIdx.x * 64 + wave * 16;
    int b = mrow0 >> 11, s_base = mrow0 & 2047;

    __shared__ short Ab[2][128][40];          // [buf][hp][k] pitch 80B (16B-aligned rows)
    int shp = tid >> 1, skp = (tid & 1) * 16; // staging: thread -> (hp, k-half)
    const short* aglob = Amat_bf + (size_t)shp * Dn + skp;
    const float* hptr = hidden + (size_t)(mrow0 + l15) * Dn + koff;

    f32x4 acc[8] = {};
    // prologue: stage chunk 0 directly; prefetch hidden chunks 0,1
    {
        short8 s0 = *(const short8*)(aglob);
        short8 s1 = *(const short8*)(aglob + 8);
        *(short8*)(&Ab[0][shp][skp]) = s0;
        *(short8*)(&Ab[0][shp][skp + 8]) = s1;
    }
    f32x4 ha = *(const f32x4*)(hptr);
    f32x4 hb = *(const f32x4*)(hptr + 4);
    f32x4 ha1 = *(const f32x4*)(hptr + 32);
    f32x4 hb1 = *(const f32x4*)(hptr + 36);

    for (int ic = 0; ic < 32; ic++) {
        int cur = ic & 1;
        short8 nA0 = {}, nA1 = {};
        f32x4 nh0 = {}, nh1 = {};
        if (ic + 1 < 32) {
            nA0 = *(const short8*)(aglob + (ic + 1) * 32);
            nA1 = *(const short8*)(aglob + (ic + 1) * 32 + 8);
        }
        if (ic + 2 < 32) {
            nh0 = *(const f32x4*)(hptr + (ic + 2) * 32);
            nh1 = *(const f32x4*)(hptr + (ic + 2) * 32 + 4);
        }
        __syncthreads();                      // buf[cur] writes visible
        short8 av;
#pragma unroll
        for (int i = 0; i < 4; i++) { av[i] = f2bf(ha[i]); av[i + 4] = f2bf(hb[i]); }
#pragma unroll
        for (int nt = 0; nt < 8; nt++) {
            short8 bv = *(const short8*)(&Ab[cur][nt * 16 + l15][koff]);
            acc[nt] = __builtin_amdgcn_mfma_f32_16x16x32_bf16(av, bv, acc[nt], 0, 0, 0);
        }
        if (ic + 1 < 32) {
            *(short8*)(&Ab[cur ^ 1][shp][skp]) = nA0;
            *(short8*)(&Ab[cur ^ 1][shp][skp + 8]) = nA1;
        }
        ha = ha1; hb = hb1; ha1 = nh0; hb1 = nh1;
    }
    // epilogue: C/D layout col=lane&15 (hp within tile), row=(lane>>4)*4+reg (s)
    int srow = s_base + (lane >> 4) * 4;
    const unsigned char* vptr = valid + (size_t)b * Sn + srow;
    bool ok0 = vptr[0] != 0, ok1 = vptr[1] != 0, ok2 = vptr[2] != 0, ok3 = vptr[3] != 0;
#pragma unroll
    for (int nt = 0; nt < 8; nt++) {
        int hp = nt * 16 + l15;
        float cc = c0[hp];
        f32x4 st;
        st[0] = ok0 ? acc[nt][0] + cc : -1.0e9f;
        st[1] = ok1 ? acc[nt][1] + cc : -1.0e9f;
        st[2] = ok2 ? acc[nt][2] + cc : -1.0e9f;
        st[3] = ok3 ? acc[nt][3] + cc : -1.0e9f;
        *(f32x4*)(scores + (size_t)(b * 128 + hp) * Sn + srow) = st;
    }
}

// ---------------------------------------------------------------- softmax over s; writes bf16 attn
__global__ __launch_bounds__(256) void softmax_kernel(const float* __restrict__ scores,
                                                      short* __restrict__ attn_bf) {
    const float* row = scores + (size_t)blockIdx.x * Sn;
    short* orow = attn_bf + (size_t)blockIdx.x * Sn;
    int t = threadIdx.x;
    __shared__ float red[256];
    f32x4 v0 = *(const f32x4*)(row + t * 8);
    f32x4 v1 = *(const f32x4*)(row + t * 8 + 4);
    float mx = -1.0e30f;
#pragma unroll
    for (int i = 0; i < 4; i++) { mx = fmaxf(mx, v0[i]); mx = fmaxf(mx, v1[i]); }
    red[t] = mx;
    __syncthreads();
    for (int off = 128; off > 0; off >>= 1) {
        if (t < off) red[t] = fmaxf(red[t], red[t + off]);
        __syncthreads();
    }
    mx = red[0];
    __syncthreads();
    float e[8];
    float sum = 0.0f;
#pragma unroll
    for (int i = 0; i < 4; i++) {
        e[i] = expf(v0[i] - mx); sum += e[i];
        e[i + 4] = expf(v1[i] - mx); sum += e[i + 4];
    }
    red[t] = sum;
    __syncthreads();
    for (int off = 128; off > 0; off >>= 1) {
        if (t < off) red[t] += red[t + off];
        __syncthreads();
    }
    float inv = 1.0f / red[0];
    short8 o;
#pragma unroll
    for (int i = 0; i < 8; i++) o[i] = f2bf(e[i] * inv);
    *(short8*)(orow + t * 8) = o;
}

// ---------------------------------------------------------------- U partials: Up[b,hp,c] = sum_{s in z-chunk} attn[b,hp,s]*hidden[b,s,c]
__global__ __launch_bounds__(512) void U_mfma(const short* __restrict__ attn_bf,
                                              const float* __restrict__ hidden,
                                              float* __restrict__ Up0,
                                              float* __restrict__ Up1,
                                              float* __restrict__ Up2) {
    int b = blockIdx.y, n0 = blockIdx.x * 64, z = blockIdx.z;
    int zbase = z * 704;
    int zlen = (z == 2) ? 640 : 704;
    float* Up = (z == 0) ? Up0 : (z == 1) ? Up1 : Up2;

    int tid = threadIdx.x, wave = tid >> 6, lane = tid & 63;
    int l15 = lane & 15;
    __shared__ short ldsB[2][64][40];
    int kr = tid & 31, nc = ((tid >> 5) & 15) * 4; // staging: (k=kr, c=nc..nc+3)
    int koff = (lane >> 4) * 8;
    f32x4 acc[4] = {};
    const short* aBase = attn_bf + ((size_t)b * 128 + wave * 16 + l15) * Sn + zbase + koff;
    const float* hBase = hidden + ((size_t)b * Sn + zbase + kr) * Dn + n0 + nc;

    int nk = zlen >> 5;                       // 22 or 20 chunks
    f32x4 h = *(const f32x4*)(hBase);
#pragma unroll
    for (int i = 0; i < 4; i++) ldsB[0][nc + i][kr] = f2bf(h[i]);
    short8 av = *(const short8*)(aBase);

    for (int ic = 0; ic < nk; ic++) {
        int cur = ic & 1;
        bool more = (ic + 1 < nk);
        f32x4 hn;
        short8 avn;
        if (more) {
            hn = *(const f32x4*)(hBase + (size_t)(ic + 1) * 32 * Dn);
            avn = *(const short8*)(aBase + (ic + 1) * 32);
        }
        __syncthreads();                      // buf[cur] writes visible
#pragma unroll
        for (int nf = 0; nf < 4; nf++) {
            short8 bv = *(const short8*)(&ldsB[cur][nf * 16 + l15][koff]);
            acc[nf] = __builtin_amdgcn_mfma_f32_16x16x32_bf16(av, bv, acc[nf], 0, 0, 0);
        }
        if (more) {
#pragma unroll
            for (int i = 0; i < 4; i++) ldsB[cur ^ 1][nc + i][kr] = f2bf(hn[i]);
            av = avn;
        }
    }
    int hp = wave * 16 + (lane >> 4) * 4;
#pragma unroll
    for (int nf = 0; nf < 4; nf++) {
        int c = n0 + nf * 16 + l15;
        float* up = Up + (size_t)(b * 128 + hp) * Dn + c;
#pragma unroll
        for (int r = 0; r < 4; r++) up[(size_t)r * Dn] = acc[nf][r];
    }
}

// ---------------------------------------------------------------- ctx[bp, h*64+d] = (Up0+Up1+Up2)[b,h*8+p,:] . Wv[h*64+d,:] + bv  (MFMA)
// grid 256 = (b,h), 64 threads. A rows = p (0-7, duplicated to 16); sum of 3
// partials + cvt fused into A-frag load; Wv read f32 + in-reg cvt.
__global__ __launch_bounds__(64) void ctx_mfma(const float* __restrict__ Up0,
                                               const float* __restrict__ Up1,
                                               const float* __restrict__ Up2,
                                               const float* __restrict__ in_w,
                                               const float* __restrict__ in_b,
                                               float* __restrict__ ctx) {
    int bh = blockIdx.x, b = bh >> 4, h = bh & 15;
    int lane = threadIdx.x & 63, l15 = lane & 15, koff = (lane >> 4) * 8;
    int p = l15 & 7;
    size_t uoff = ((size_t)b * 128 + h * 8 + p) * Dn + koff;
    const float* wv = in_w + (size_t)(2 * Dn + h * 64 + l15) * Dn + koff;
    f32x4 acc[4] = {};
    for (int k0 = 0; k0 < Dn; k0 += 32) {
        f32x4 a0 = *(const f32x4*)(Up0 + uoff + k0);
        f32x4 a1 = *(const f32x4*)(Up0 + uoff + k0 + 4);
        f32x4 b0 = *(const f32x4*)(Up1 + uoff + k0);
        f32x4 b1 = *(const f32x4*)(Up1 + uoff + k0 + 4);
        f32x4 d0 = *(const f32x4*)(Up2 + uoff + k0);
        f32x4 d1 = *(const f32x4*)(Up2 + uoff + k0 + 4);
        short8 av;
#pragma unroll
        for (int i = 0; i < 4; i++) {
            av[i] = f2bf(a0[i] + b0[i] + d0[i]);
            av[i + 4] = f2bf(a1[i] + b1[i] + d1[i]);
        }
#pragma unroll
        for (int nt = 0; nt < 4; nt++) {
            f32x4 w0 = *(const f32x4*)(wv + (size_t)nt * 16 * Dn + k0);
            f32x4 w1 = *(const f32x4*)(wv + (size_t)nt * 16 * Dn + k0 + 4);
            short8 bv;
#pragma unroll
            for (int i = 0; i < 4; i++) { bv[i] = f2bf(w0[i]); bv[i + 4] = f2bf(w1[i]); }
            acc[nt] = __builtin_amdgcn_mfma_f32_16x16x32_bf16(av, bv, acc[nt], 0, 0, 0);
        }
    }
    if (lane < 32) {                          // rows 0-7 valid (p)
        int prow = (lane >> 4) * 4;
#pragma unroll
        for (int nt = 0; nt < 4; nt++) {
            int d = h * 64 + nt * 16 + l15;
            float bias = in_b[2 * Dn + d];
#pragma unroll
            for (int r = 0; r < 4; r++)
                ctx[(size_t)(b * 8 + prow + r) * Dn + d] = acc[nt][r] + bias;
        }
    }
}

// ---------------------------------------------------------------- pooled = ctx @ out_w^T + out_b (MFMA, f32 operands cvt in-reg)
__global__ __launch_bounds__(256) void pooled_mfma(const float* __restrict__ A,
                                                   const float* __restrict__ B,
                                                   const float* __restrict__ bias,
                                                   float* __restrict__ C, int M) {
    int wave = threadIdx.x >> 6, lane = threadIdx.x & 63;
    int l15 = lane & 15, koff = (lane >> 4) * 8;
    int m0 = blockIdx.x * 64 + (wave >> 1) * 32;
    int n0 = blockIdx.y * 64 + (wave & 1) * 32;
    f32x4 acc[2][2] = {};
    int ra0 = min(m0 + l15, M - 1);
    int ra1 = min(m0 + 16 + l15, M - 1);
    const float* a0p = A + (size_t)ra0 * Dn + koff;
    const float* a1p = A + (size_t)ra1 * Dn + koff;
    const float* b0p = B + (size_t)(n0 + l15) * Dn + koff;
    const float* b1p = B + (size_t)(n0 + 16 + l15) * Dn + koff;
    for (int k0 = 0; k0 < Dn; k0 += 32) {
        short8 av0, av1, bv0, bv1;
        f32x4 x, y;
        x = *(const f32x4*)(a0p + k0); y = *(const f32x4*)(a0p + k0 + 4);
#pragma unroll
        for (int i = 0; i < 4; i++) { av0[i] = f2bf(x[i]); av0[i + 4] = f2bf(y[i]); }
        x = *(const f32x4*)(a1p + k0); y = *(const f32x4*)(a1p + k0 + 4);
#pragma unroll
        for (int i = 0; i < 4; i++) { av1[i] = f2bf(x[i]); av1[i + 4] = f2bf(y[i]); }
        x = *(const f32x4*)(b0p + k0); y = *(const f32x4*)(b0p + k0 + 4);
#pragma unroll
        for (int i = 0; i < 4; i++) { bv0[i] = f2bf(x[i]); bv0[i + 4] = f2bf(y[i]); }
        x = *(const f32x4*)(b1p + k0); y = *(const f32x4*)(b1p + k0 + 4);
#pragma unroll
        for (int i = 0; i < 4; i++) { bv1[i] = f2bf(x[i]); bv1[i + 4] = f2bf(y[i]); }
        acc[0][0] = __builtin_amdgcn_mfma_f32_16x16x32_bf16(av0, bv0, acc[0][0], 0, 0, 0);
        acc[0][1] = __builtin_amdgcn_mfma_f32_16x16x32_bf16(av0, bv1, acc[0][1], 0, 0, 0);
        acc[1][0] = __builtin_amdgcn_mfma_f32_16x16x32_bf16(av1, bv0, acc[1][0], 0, 0, 0);
        acc[1][1] = __builtin_amdgcn_mfma_f32_16x16x32_bf16(av1, bv1, acc[1][1], 0, 0, 0);
    }
#pragma unroll
    for (int mf = 0; mf < 2; mf++) {
        int row0 = m0 + mf * 16 + (lane >> 4) * 4;
#pragma unroll
        for (int nf = 0; nf < 2; nf++) {
            int col = n0 + nf * 16 + l15;
            float bval = bias[col];
#pragma unroll
            for (int r = 0; r < 4; r++) {
                int row = row0 + r;
                if (row < M) C[(size_t)row * Dn + col] = acc[mf][nf][r] + bval;
            }
        }
    }
}

// ---------------------------------------------------------------- bf16 MFMA GEMM: C[M,1024] = A_bf[M,1024] @ B_bf[1024,1024]^T + bias
__global__ __launch_bounds__(256) void wgemm_mfma(const short* __restrict__ Abf,
                                                  const short* __restrict__ Bbf,
                                                  const float* __restrict__ bias,
                                                  float* __restrict__ C, int M) {
    int wave = threadIdx.x >> 6, lane = threadIdx.x & 63;
    int m0 = blockIdx.x * 64 + (wave >> 1) * 32;
    int n0 = blockIdx.y * 64 + (wave & 1) * 32;
    int koff = (lane >> 4) * 8;
    f32x4 acc[2][2] = {};
    int ra0 = min(m0 + (lane & 15), M - 1);
    int ra1 = min(m0 + 16 + (lane & 15), M - 1);
    const short* a0p = Abf + (size_t)ra0 * Dn + koff;
    const short* a1p = Abf + (size_t)ra1 * Dn + koff;
    const short* b0p = Bbf + (size_t)(n0 + (lane & 15)) * Dn + koff;
    const short* b1p = Bbf + (size_t)(n0 + 16 + (lane & 15)) * Dn + koff;
    for (int k0 = 0; k0 < Dn; k0 += 32) {
        short8 av0 = *(const short8*)(a0p + k0);
        short8 av1 = *(const short8*)(a1p + k0);
        short8 bv0 = *(const short8*)(b0p + k0);
        short8 bv1 = *(const short8*)(b1p + k0);
        acc[0][0] = __builtin_amdgcn_mfma_f32_16x16x32_bf16(av0, bv0, acc[0][0], 0, 0, 0);
        acc[0][1] = __builtin_amdgcn_mfma_f32_16x16x32_bf16(av0, bv1, acc[0][1], 0, 0, 0);
        acc[1][0] = __builtin_amdgcn_mfma_f32_16x16x32_bf16(av1, bv0, acc[1][0], 0, 0, 0);
        acc[1][1] = __builtin_amdgcn_mfma_f32_16x16x32_bf16(av1, bv1, acc[1][1], 0, 0, 0);
    }
#pragma unroll
    for (int mf = 0; mf < 2; mf++) {
        int row0 = m0 + mf * 16 + (lane >> 4) * 4;
#pragma unroll
        for (int nf = 0; nf < 2; nf++) {
            int col = n0 + nf * 16 + (lane & 15);
            float bval = bias[col];
#pragma unroll
            for (int r = 0; r < 4; r++) {
                int row = row0 + r;
                if (row < M) C[(size_t)row * Dn + col] = acc[mf][nf][r] + bval;
            }
        }
    }
}

// ---------------------------------------------------------------- block sum helper
__device__ __forceinline__ float block_sum(float v, float* red) {
    int tid = threadIdx.x;
    red[tid] = v;
    __syncthreads();
    for (int off = 128; off > 0; off >>= 1) {
        if (tid < off) red[tid] += red[tid + off];
        __syncthreads();
    }
    float r = red[0];
    __syncthreads();
    return r;
}

// ---------------------------------------------------------------- build summary row + LN_pma + LN_v / LN_g (bf16 out)
__global__ void summary_ln_kernel(const float* __restrict__ hidden,
                                  const float* __restrict__ queries,
                                  const float* __restrict__ pooled,
                                  const int* __restrict__ rsrc,
                                  const float* __restrict__ gpma, const float* __restrict__ bpma,
                                  const float* __restrict__ gv, const float* __restrict__ bv,
                                  const float* __restrict__ gg, const float* __restrict__ bg,
                                  short* __restrict__ lnv, short* __restrict__ lng) {
    __shared__ float red[256];
    int b = blockIdx.x, t = blockIdx.y, tid = threadIdx.x;
    float x[4];
    if (t == 0) {
#pragma unroll
        for (int i = 0; i < 4; i++)
            x[i] = hidden[(size_t)b * Sn * Dn + tid + i * 256];
    } else if (t < 1 + Pn) {
        int p = t - 1;
#pragma unroll
        for (int i = 0; i < 4; i++) {
            int c = tid + i * 256;
            x[i] = queries[p * Dn + c] + pooled[((size_t)b * Pn + p) * Dn + c];
        }
    } else {
        int src = rsrc[b * RECn + (t - 9)];
        if (src >= 0) {
#pragma unroll
            for (int i = 0; i < 4; i++)
                x[i] = hidden[((size_t)b * Sn + src) * Dn + tid + i * 256];
        } else {
#pragma unroll
            for (int i = 0; i < 4; i++) x[i] = 0.0f;
        }
    }
    if (t >= 1 && t < 1 + Pn) {
        float mu = block_sum(x[0] + x[1] + x[2] + x[3], red) * (1.0f / Dn);
        float d2 = 0.0f;
#pragma unroll
        for (int i = 0; i < 4; i++) { float d = x[i] - mu; d2 += d * d; }
        float inv = rsqrtf(block_sum(d2, red) * (1.0f / Dn) + 1e-5f);
#pragma unroll
        for (int i = 0; i < 4; i++) {
            int c = tid + i * 256;
            x[i] = (x[i] - mu) * inv * gpma[c] + bpma[c];
        }
    }
    float mu = block_sum(x[0] + x[1] + x[2] + x[3], red) * (1.0f / Dn);
    float d2 = 0.0f;
#pragma unroll
    for (int i = 0; i < 4; i++) { float d = x[i] - mu; d2 += d * d; }
    float inv = rsqrtf(block_sum(d2, red) * (1.0f / Dn) + 1e-5f);
    size_t row = (size_t)(b * Tn + t) * Dn;
#pragma unroll
    for (int i = 0; i < 4; i++) {
        int c = tid + i * 256;
        float xh = (x[i] - mu) * inv;
        lnv[row + c] = f2bf(xh * gv[c] + bv[c]);
        lng[row + c] = f2bf(xh * gg[c] + bg[c]);
    }
}

// ---------------------------------------------------------------- gated = sigmoid(c2) * silu(c1) * mask
__global__ void gated_kernel(const float* __restrict__ c1, const float* __restrict__ c2,
                             const float* __restrict__ maskf, float* __restrict__ out) {
    int gi = blockIdx.x * blockDim.x + threadIdx.x;
    int row = gi >> 10;
    float m = maskf[row];
    float a = c1[gi], g = c2[gi];
    float sv = a / (1.0f + expf(-a));
    float sg = 1.0f / (1.0f + expf(-g));
    out[gi] = sg * sv * m;
}

// ================================================================ launch
extern "C" void kernel_launch(void* const* d_in, const int* in_sizes, int n_in,
                              void* d_out, int out_size, void* d_ws, size_t ws_size,
                              hipStream_t stream) {
    const float* hidden = (const float*)d_in[0];
    const void* valid_raw = d_in[1];
    const float* queries = (const float*)d_in[2];
    const float* in_w = (const float*)d_in[3];
    const float* in_b = (const float*)d_in[4];
    const float* out_w = (const float*)d_in[5];
    const float* out_b = (const float*)d_in[6];
    const float* ln_pma_g = (const float*)d_in[7];
    const float* ln_pma_b = (const float*)d_in[8];
    const float* ln_v_g = (const float*)d_in[9];
    const float* ln_v_b = (const float*)d_in[10];
    const float* W_v = (const float*)d_in[11];
    const float* b_v = (const float*)d_in[12];
    const float* ln_g_g = (const float*)d_in[13];
    const float* ln_g_b = (const float*)d_in[14];
    const float* W_g = (const float*)d_in[15];
    const float* b_g = (const float*)d_in[16];

    float* ws = (float*)d_ws;
    float* out = (float*)d_out;

    // workspace layout (float offsets):
    float* SC      = ws;                         // scores f32: 4,194,304 f (dead after softmax)
    short* attn_bf = (short*)(ws + 4194304);     // 2,097,152 f worth
    float* Up0     = ws + 6291456;               // 2,097,152 f
    float* Up1     = ws;                         // overlay in dead SC region
    float* Up2     = ws + 2097152;               // overlay in dead SC region
    float* qbuf    = ws + 8388608;               // 8,192
    short* Amat_bf = (short*)(ws + 8396800);     // 65,536 f
    float* c0      = ws + 8462336;               // 256
    float* ctx     = ws + 8462592;               // 131,072
    float* pooled  = ws + 8593664;               // 131,072
    short* Wv_bf   = (short*)(ws + 8724736);     // 524,288 f
    short* Wg_bf   = (short*)(ws + 9249024);     // 524,288 f
    int*   ivals   = (int*)(ws + 9773312);
    int* totals = ivals;                         // 16
    int* rsrc = ivals + 16;                      // 1024
    int* flag = ivals + 16 + 1024;               // 16
    unsigned char* canon = (unsigned char*)(ivals + 16 + 1024 + 16); // 32768 B
    // post-ctx overlays in SC region (Up1/Up2 dead after ctx):
    short* lnv_bf = (short*)ws;                  // 598,016 f worth
    short* lng_bf = (short*)(ws + 622592);
    float* c1 = ws + 1245184;
    float* c2 = ws + 2441216;                    // ends 3,637,248 < 4,194,304 OK
    float* maskf = out + (size_t)Bn * Tn * Dn;

    const int M2 = Bn * Tn; // 1168

    detect_mask_kernel<<<1, 256, 0, stream>>>((const unsigned char*)valid_raw, flag);
    canon_mask_kernel<<<(Bn * Sn) / 256, 256, 0, stream>>>(valid_raw, flag, canon);
    prep_kernel<<<Bn, 256, 0, stream>>>(canon, totals, rsrc, maskf);
    q_kernel<<<(Pn * Dn) / 4, 256, 0, stream>>>(queries, in_w, in_b, qbuf);
    A_kernel<<<dim3(Hn, 4), 256, 0, stream>>>(qbuf, in_w, in_b, Amat_bf, c0);
    wcvt_kernel<<<512, 256, 0, stream>>>(W_v, Wv_bf, Dn * Dn);
    wcvt_kernel<<<512, 256, 0, stream>>>(W_g, Wg_bf, Dn * Dn);
    scores_mfma<<<(Bn * Sn) / 64, 256, 0, stream>>>(hidden, Amat_bf, c0, canon, SC);
    softmax_kernel<<<Bn * 128, 256, 0, stream>>>(SC, attn_bf);
    U_mfma<<<dim3(16, Bn, 3), 512, 0, stream>>>(attn_bf, hidden, Up0, Up1, Up2);
    ctx_mfma<<<Bn * Hn, 64, 0, stream>>>(Up0, Up1, Up2, in_w, in_b, ctx);
    pooled_mfma<<<dim3(2, 16), 256, 0, stream>>>(ctx, out_w, out_b, pooled, Bn * Pn);
    summary_ln_kernel<<<dim3(Bn, Tn), 256, 0, stream>>>(hidden, queries, pooled, rsrc,
                                                        ln_pma_g, ln_pma_b, ln_v_g, ln_v_b,
                                                        ln_g_g, ln_g_b, lnv_bf, lng_bf);
    wgemm_mfma<<<dim3((M2 + 63) / 64, 16), 256, 0, stream>>>(lnv_bf, Wv_bf, b_v, c1, M2);
    wgemm_mfma<<<dim3((M2 + 63) / 64, 16), 256, 0, stream>>>(lng_bf, Wg_bf, b_g, c2, M2);
    gated_kernel<<<(Bn * Tn * Dn) / 256, 256, 0, stream>>>(c1, c2, maskf, out);
}